// Round 16
// baseline (138.643 us; speedup 1.0000x reference)
//
#include <hip/hip_runtime.h>
#include <hip/hip_bf16.h>

// ---------- common ----------
typedef __attribute__((ext_vector_type(8))) short short8;
typedef __attribute__((ext_vector_type(4))) float f32x4;
typedef __attribute__((ext_vector_type(4))) unsigned short ushort4v;

#define DI __device__ __forceinline__

DI unsigned short f2bf(float f) {
  union { float f; unsigned int u; } a; a.f = f;
  unsigned int u = a.u;
  return (unsigned short)((u + 0x7FFFu + ((u >> 16) & 1u)) >> 16);
}

#define BARRIER() do { asm volatile("" ::: "memory"); __builtin_amdgcn_s_barrier(); asm volatile("" ::: "memory"); } while (0)
#define GLOAD16(src, dst) __builtin_amdgcn_global_load_lds( \
    (const __attribute__((address_space(1))) void*)(src), \
    (__attribute__((address_space(3))) void*)(dst), 16, 0, 0)

// Problem: B=8, H1=W1=56, N1=3136, C1=512, C2=256, NH=8, HD=64, WS=7, M=25088

// ---------- weight f32 -> bf16 converts only (fast, unblocks qpool) ----------
__global__ __launch_bounds__(256)
void wcvt(const float* __restrict__ Wq, const float* __restrict__ Wkv,
          const float* __restrict__ Wproj, const float* __restrict__ Wsr,
          unsigned short* __restrict__ Wq_b, unsigned short* __restrict__ Wkv_b,
          unsigned short* __restrict__ Wproj_b, unsigned short* __restrict__ Wsr_b) {
  long i = (long)blockIdx.x * 1024 + threadIdx.x * 4;
  const float* src; unsigned short* dst; long off;
  if (i < 262144L)      { src = Wq;    dst = Wq_b;    off = i; }
  else if (i < 524288L) { src = Wkv;   dst = Wkv_b;   off = i - 262144L; }
  else if (i < 786432L) { src = Wproj; dst = Wproj_b; off = i - 524288L; }
  else                  { src = Wsr;   dst = Wsr_b;   off = i - 786432L; }
  float4 v = *(const float4*)&src[off];
  ushort4v o = { f2bf(v.x), f2bf(v.y), f2bf(v.z), f2bf(v.w) };
  *(ushort4v*)&dst[off] = o;
}

// ---------- q-window scatter epilogue ----------
DI void epi_q(int gm, int gc, float v, unsigned short* outp) {
  const int b = gm / 3136, pos = gm % 3136;
  const int h = pos / 56, ww = pos % 56;
  const int head = gc >> 6, d = gc & 63;
  const size_t idx = ((((size_t)(b * 8 + head)) * 64 + (h / 7) * 8 + (ww / 7)) * 49
                      + (h % 7) * 7 + (ww % 7)) * 64 + d;
  outp[idx] = f2bf(v);
}

// ---------- merged: q-proj GEMM (blocks 0..195) | 2x2 avgpool+cvt (196..3331) ----------
// The pool (103MB HBM-bound) backfills CUs left idle by the 196-block compute-bound GEMM
// and absorbs its stall cycles (grid-level memory/compute overlap).
__global__ __launch_bounds__(512, 2)
void qpool(const float* __restrict__ A,            // x (f32)
           const unsigned short* __restrict__ Bw,  // Wq_b
           unsigned short* __restrict__ outp,      // q_win
           const float* __restrict__ y,
           unsigned short* __restrict__ pooled) {
  __shared__ unsigned short lds[65536];
  const int bid = blockIdx.x;
  const int tid = threadIdx.x;

  if (bid >= 196) {
    // ---- pool: 8 pooled pixels per 512-thr block ----
    int pix = (bid - 196) * 8 + (tid >> 6);
    int cv = (tid & 63) * 4;
    int b = pix / 3136, p = pix % 3136;
    int hp = p / 56, wp = p % 56;
    const float* src = y + (((size_t)b * 12544) + hp * 224 + wp * 2) * 256 + cv;
    float4 a0 = *(const float4*)(src);
    float4 a1 = *(const float4*)(src + 256);
    float4 a2 = *(const float4*)(src + 28672);
    float4 a3 = *(const float4*)(src + 28672 + 256);
    float4 av;
    av.x = (a0.x + a1.x + a2.x + a3.x) * 0.25f;
    av.y = (a0.y + a1.y + a2.y + a3.y) * 0.25f;
    av.z = (a0.z + a1.z + a2.z + a3.z) * 0.25f;
    av.w = (a0.w + a1.w + a2.w + a3.w) * 0.25f;
    ushort4v o = { f2bf(av.x), f2bf(av.y), f2bf(av.z), f2bf(av.w) };
    *(ushort4v*)&pooled[(size_t)pix * 256 + cv] = o;
    return;
  }

  // ---- q-proj GEMM (verified gemm256f body) ----
  const int wv = tid >> 6;
  const int lane = tid & 63;
  const int lr = lane & 15;
  const int lg = lane >> 4;
  const int lr4 = lg * 4;
  const int srow8 = lane >> 3;
  const int sl8 = lane & 7;
  const int wm = wv >> 2;
  const int wn = wv & 3;
  const int m0 = (bid >> 1) * 256;
  const int n0 = (bid & 1) * 256;
  constexpr int K = 512, NT = K / 64;

  f32x4 acc[8][4];
#pragma unroll
  for (int i = 0; i < 8; ++i)
#pragma unroll
    for (int j = 0; j < 4; ++j) acc[i][j] = (f32x4){0.f, 0.f, 0.f, 0.f};

  float4 fa[4][2];
  auto loadA = [&](int t1) {
    int tsrc = (t1 < NT) ? t1 : NT - 1;
#pragma unroll
    for (int rr = 0; rr < 4; ++rr) {
      int trow = rr * 64 + wv * 8 + srow8;
      const float* p = A + (size_t)(m0 + trow) * K + tsrc * 64 + sl8 * 8;
      fa[rr][0] = *(const float4*)p;
      fa[rr][1] = *(const float4*)(p + 4);
    }
    asm volatile("" ::: "memory");
  };
  auto writeA = [&](int t1) {
#pragma unroll
    for (int rr = 0; rr < 4; ++rr) {
      int trow = rr * 64 + wv * 8 + srow8;
      union { short8 s; unsigned short u[8]; } w;
      w.u[0] = f2bf(fa[rr][0].x); w.u[1] = f2bf(fa[rr][0].y);
      w.u[2] = f2bf(fa[rr][0].z); w.u[3] = f2bf(fa[rr][0].w);
      w.u[4] = f2bf(fa[rr][1].x); w.u[5] = f2bf(fa[rr][1].y);
      w.u[6] = f2bf(fa[rr][1].z); w.u[7] = f2bf(fa[rr][1].w);
      *(short8*)&lds[(t1 & 1) * 32768 + trow * 64 + ((sl8 ^ (trow & 7)) * 8)] = w.s;
    }
  };
  auto stageB = [&](int t1, int rr) {
    int tsrc = (t1 < NT) ? t1 : NT - 1;
    int trow = rr * 64 + wv * 8 + srow8;
    int sx = sl8 ^ (trow & 7);
    GLOAD16(Bw + (size_t)(n0 + trow) * K + tsrc * 64 + sx * 8,
            &lds[(t1 & 1) * 32768 + 16384 + (rr * 64 + wv * 8) * 64]);
  };
  auto rdA = [&](int s, int mf, int ks) -> short8 {
    int row = wm * 128 + mf * 16 + lr;
    int slot = ((ks << 2) + lg) ^ (row & 7);
    return *(const short8*)&lds[s * 32768 + row * 64 + slot * 8];
  };
  auto rdB = [&](int s, int nf, int ks) -> short8 {
    int row = wn * 64 + nf * 16 + lr;
    int slot = ((ks << 2) + lg) ^ (row & 7);
    return *(const short8*)&lds[s * 32768 + 16384 + row * 64 + slot * 8];
  };

  stageB(0, 0); stageB(0, 1); stageB(0, 2); stageB(0, 3);
  loadA(0);
  asm volatile("s_waitcnt vmcnt(0)" ::: "memory");
  writeA(0);
  asm volatile("s_waitcnt lgkmcnt(0)" ::: "memory");
  BARRIER();

  for (int t = 0; t < NT; ++t) {
    const int s = t & 1;
    short8 bfr[4][2];
    loadA(t + 1);
#pragma unroll
    for (int j = 0; j < 4; ++j) { bfr[j][0] = rdB(s, j, 0); bfr[j][1] = rdB(s, j, 1); }
    {
      short8 x0 = rdA(s, 0, 0), x1 = rdA(s, 0, 1);
      short8 y0 = rdA(s, 1, 0), y1 = rdA(s, 1, 1);
      BARRIER();
      __builtin_amdgcn_s_setprio(1);
#pragma unroll
      for (int j = 0; j < 4; ++j) {
        acc[0][j] = __builtin_amdgcn_mfma_f32_16x16x32_bf16(x0, bfr[j][0], acc[0][j], 0, 0, 0);
        acc[0][j] = __builtin_amdgcn_mfma_f32_16x16x32_bf16(x1, bfr[j][1], acc[0][j], 0, 0, 0);
        acc[1][j] = __builtin_amdgcn_mfma_f32_16x16x32_bf16(y0, bfr[j][0], acc[1][j], 0, 0, 0);
        acc[1][j] = __builtin_amdgcn_mfma_f32_16x16x32_bf16(y1, bfr[j][1], acc[1][j], 0, 0, 0);
      }
      __builtin_amdgcn_s_setprio(0);
      BARRIER();
    }
    stageB(t + 1, 0); stageB(t + 1, 1);
    {
      short8 x0 = rdA(s, 2, 0), x1 = rdA(s, 2, 1);
      short8 y0 = rdA(s, 3, 0), y1 = rdA(s, 3, 1);
      BARRIER();
      __builtin_amdgcn_s_setprio(1);
#pragma unroll
      for (int j = 0; j < 4; ++j) {
        acc[2][j] = __builtin_amdgcn_mfma_f32_16x16x32_bf16(x0, bfr[j][0], acc[2][j], 0, 0, 0);
        acc[2][j] = __builtin_amdgcn_mfma_f32_16x16x32_bf16(x1, bfr[j][1], acc[2][j], 0, 0, 0);
        acc[3][j] = __builtin_amdgcn_mfma_f32_16x16x32_bf16(y0, bfr[j][0], acc[3][j], 0, 0, 0);
        acc[3][j] = __builtin_amdgcn_mfma_f32_16x16x32_bf16(y1, bfr[j][1], acc[3][j], 0, 0, 0);
      }
      __builtin_amdgcn_s_setprio(0);
      BARRIER();
    }
    stageB(t + 1, 2); stageB(t + 1, 3);
    {
      short8 x0 = rdA(s, 4, 0), x1 = rdA(s, 4, 1);
      short8 y0 = rdA(s, 5, 0), y1 = rdA(s, 5, 1);
      BARRIER();
      __builtin_amdgcn_s_setprio(1);
#pragma unroll
      for (int j = 0; j < 4; ++j) {
        acc[4][j] = __builtin_amdgcn_mfma_f32_16x16x32_bf16(x0, bfr[j][0], acc[4][j], 0, 0, 0);
        acc[4][j] = __builtin_amdgcn_mfma_f32_16x16x32_bf16(x1, bfr[j][1], acc[4][j], 0, 0, 0);
        acc[5][j] = __builtin_amdgcn_mfma_f32_16x16x32_bf16(y0, bfr[j][0], acc[5][j], 0, 0, 0);
        acc[5][j] = __builtin_amdgcn_mfma_f32_16x16x32_bf16(y1, bfr[j][1], acc[5][j], 0, 0, 0);
      }
      __builtin_amdgcn_s_setprio(0);
      BARRIER();
    }
    {
      short8 x0 = rdA(s, 6, 0), x1 = rdA(s, 6, 1);
      short8 y0 = rdA(s, 7, 0), y1 = rdA(s, 7, 1);
      asm volatile("s_waitcnt vmcnt(4)" ::: "memory");
      writeA(t + 1);
      asm volatile("s_waitcnt lgkmcnt(0)" ::: "memory");
      BARRIER();
      __builtin_amdgcn_s_setprio(1);
#pragma unroll
      for (int j = 0; j < 4; ++j) {
        acc[6][j] = __builtin_amdgcn_mfma_f32_16x16x32_bf16(x0, bfr[j][0], acc[6][j], 0, 0, 0);
        acc[6][j] = __builtin_amdgcn_mfma_f32_16x16x32_bf16(x1, bfr[j][1], acc[6][j], 0, 0, 0);
        acc[7][j] = __builtin_amdgcn_mfma_f32_16x16x32_bf16(y0, bfr[j][0], acc[7][j], 0, 0, 0);
        acc[7][j] = __builtin_amdgcn_mfma_f32_16x16x32_bf16(y1, bfr[j][1], acc[7][j], 0, 0, 0);
      }
      __builtin_amdgcn_s_setprio(0);
      asm volatile("s_waitcnt vmcnt(0)" ::: "memory");
      BARRIER();
    }
  }

#pragma unroll
  for (int i = 0; i < 8; ++i)
#pragma unroll
    for (int j = 0; j < 4; ++j)
#pragma unroll
      for (int r = 0; r < 4; ++r)
        epi_q(m0 + wm * 128 + i * 16 + lr4 + r, n0 + wn * 64 + j * 16 + lr,
              acc[i][j][r], outp);
}

// ---------- fused 1x1 conv GEMM -> +bias -> LN -> GELU (verified standalone form) ----------
__global__ __launch_bounds__(256)
void sr_gemm(const unsigned short* __restrict__ Ap, const unsigned short* __restrict__ Wsr_b,
             const float* __restrict__ bsr, const float* __restrict__ gn,
             const float* __restrict__ bn, unsigned short* __restrict__ out) {
  __shared__ unsigned short sA[64 * 64];
  __shared__ unsigned short sB[256 * 64];
  __shared__ float red[64 * 8];

  const int tid = threadIdx.x;
  const int wv = tid >> 6;
  const int lane = tid & 63;
  const int lr = lane & 15;
  const int lg = lane >> 4;
  const int lr4 = lg * 4;
  const int m0 = blockIdx.x * 64;
  const int sr8 = lane >> 3;
  const int sl8 = lane & 7;

  f32x4 acc[4][4];
#pragma unroll
  for (int i = 0; i < 4; ++i)
#pragma unroll
    for (int j = 0; j < 4; ++j) acc[i][j] = (f32x4){0.f, 0.f, 0.f, 0.f};

  for (int kt = 0; kt < 256; kt += 64) {
#pragma unroll
    for (int c = 0; c < 2; ++c) {
      int row = wv * 16 + c * 8 + sr8;
      GLOAD16(Ap + (size_t)(m0 + row) * 256 + kt + ((sl8 ^ (row & 7)) * 8),
              &sA[(wv * 16 + c * 8) * 64]);
    }
#pragma unroll
    for (int c = 0; c < 8; ++c) {
      int row = wv * 64 + c * 8 + sr8;
      GLOAD16(Wsr_b + (size_t)row * 256 + kt + ((sl8 ^ (row & 7)) * 8),
              &sB[(wv * 64 + c * 8) * 64]);
    }
    __syncthreads();
#pragma unroll
    for (int ks = 0; ks < 2; ++ks) {
      short8 af[4], bfr[4];
#pragma unroll
      for (int i = 0; i < 4; ++i)
        af[i] = *(const short8*)&sA[(i * 16 + lr) * 64 + (((ks * 4 + lg) ^ (lr & 7)) * 8)];
#pragma unroll
      for (int j = 0; j < 4; ++j)
        bfr[j] = *(const short8*)&sB[(wv * 64 + j * 16 + lr) * 64 + (((ks * 4 + lg) ^ (lr & 7)) * 8)];
#pragma unroll
      for (int i = 0; i < 4; ++i)
#pragma unroll
        for (int j = 0; j < 4; ++j)
          acc[i][j] = __builtin_amdgcn_mfma_f32_16x16x32_bf16(af[i], bfr[j], acc[i][j], 0, 0, 0);
    }
    __syncthreads();
  }

  float bsv[4], gnv[4], bnv[4];
#pragma unroll
  for (int j = 0; j < 4; ++j) {
    int col = wv * 64 + j * 16 + lr;
    bsv[j] = bsr[col]; gnv[j] = gn[col]; bnv[j] = bn[col];
  }
  float s_[4][4], q_[4][4];
#pragma unroll
  for (int i = 0; i < 4; ++i)
#pragma unroll
    for (int r = 0; r < 4; ++r) {
      float s = 0.f, q = 0.f;
#pragma unroll
      for (int j = 0; j < 4; ++j) {
        float v = acc[i][j][r] + bsv[j];
        acc[i][j][r] = v;
        s += v; q += v * v;
      }
      s_[i][r] = s; q_[i][r] = q;
    }
#pragma unroll
  for (int m = 1; m <= 8; m <<= 1)
#pragma unroll
    for (int i = 0; i < 4; ++i)
#pragma unroll
      for (int r = 0; r < 4; ++r) {
        s_[i][r] += __shfl_xor(s_[i][r], m);
        q_[i][r] += __shfl_xor(q_[i][r], m);
      }
  if (lr == 0) {
#pragma unroll
    for (int i = 0; i < 4; ++i)
#pragma unroll
      for (int r = 0; r < 4; ++r) {
        int row = i * 16 + lr4 + r;
        red[row * 8 + wv * 2 + 0] = s_[i][r];
        red[row * 8 + wv * 2 + 1] = q_[i][r];
      }
  }
  __syncthreads();
#pragma unroll
  for (int i = 0; i < 4; ++i) {
#pragma unroll
    for (int r = 0; r < 4; ++r) {
      int row = i * 16 + lr4 + r;
      float sum = red[row * 8 + 0] + red[row * 8 + 2] + red[row * 8 + 4] + red[row * 8 + 6];
      float sq  = red[row * 8 + 1] + red[row * 8 + 3] + red[row * 8 + 5] + red[row * 8 + 7];
      float mean = sum * (1.f / 256.f);
      float var = sq * (1.f / 256.f) - mean * mean;
      float rstd = rsqrtf(var + 1e-5f);
#pragma unroll
      for (int j = 0; j < 4; ++j) {
        float t = (acc[i][j][r] - mean) * rstd * gnv[j] + bnv[j];
        t = 0.5f * t * (1.f + erff(t * 0.70710678118654752f));
        out[(size_t)(m0 + row) * 256 + wv * 64 + j * 16 + lr] = f2bf(t);
      }
    }
  }
}

// ---------- mega-fused kv-proj + attention + out-proj: 16 waves = 8 heads x 2 halves ----------
// R8 structure (h2-major Wkv staging — do not reorder; kt-major thrashes L2, +46MB FETCH).
__global__ __launch_bounds__(1024)
void kvattn(const unsigned short* __restrict__ y2,
            const unsigned short* __restrict__ Wkv_b,
            const unsigned short* __restrict__ qwin,
            const unsigned short* __restrict__ Wproj_b,
            const float* __restrict__ bproj,
            float* __restrict__ out) {
  __shared__ unsigned short lds[81920];
  const int tid = threadIdx.x;
  const int wv16 = tid >> 6;
  const int head = wv16 >> 1;
  const int half = wv16 & 1;
  const int lane = tid & 63;
  const int lr = lane & 15;
  const int lg = lane >> 4;
  const int r8 = lane >> 3;
  const int sl8 = lane & 7;
  const int bb = blockIdx.x >> 6;
  const int win = blockIdx.x & 63;
  const int ht = win >> 3, wt = win & 7;

  unsigned short* Cy  = lds;
  unsigned short* SLh = lds + 16384 + head * 8192;
  unsigned short* OA  = lds + 16384;
  unsigned short* WPs = lds + 49152 + wv16 * 2048;

  {
    int rb = wv16 & 7;
    int m = rb * 8 + r8;
    int mm = (m < 49) ? m : 48;
    int grow = bb * 3136 + (ht * 7 + mm / 7) * 56 + wt * 7 + (mm % 7);
    int p0 = wv16 >> 3;
#pragma unroll
    for (int pp = 0; pp < 2; ++pp) {
      int panel = p0 + pp * 2;
      GLOAD16(y2 + (size_t)grow * 256 + panel * 64 + ((sl8 ^ (m & 7)) * 8),
              &Cy[panel * 4096 + rb * 512]);
    }
  }

  auto stageW = [&](int s) {  // h2-major: h2 = s>>2, kt = s&3
    int h2 = s >> 2, kt = s & 3;
#pragma unroll
    for (int c = 0; c < 4; ++c) {
      int lrow = half * 32 + c * 8 + r8;
      GLOAD16(Wkv_b + (size_t)(h2 * 512 + head * 64 + lrow) * 256 + kt * 64 + ((sl8 ^ r8) * 8),
              &SLh[(s & 1) * 4096 + (half * 32 + c * 8) * 64]);
    }
  };

  f32x4 aK[4][2], aV[4][2];
#pragma unroll
  for (int i = 0; i < 4; ++i)
#pragma unroll
    for (int j = 0; j < 2; ++j) { aK[i][j] = (f32x4){0,0,0,0}; aV[i][j] = (f32x4){0,0,0,0}; }

  stageW(0);
  asm volatile("s_waitcnt vmcnt(4)" ::: "memory");
  BARRIER();  // (1) Cy visible

#pragma unroll
  for (int s = 0; s < 8; ++s) {
    if (s < 7) {
      stageW(s + 1);
      asm volatile("s_waitcnt vmcnt(4)" ::: "memory");
    } else {
      asm volatile("s_waitcnt vmcnt(0)" ::: "memory");
    }
    const int kt = s & 3;
    const unsigned short* Wb = &SLh[(s & 1) * 4096];
    short8 bfrg[2][2];
#pragma unroll
    for (int nf2 = 0; nf2 < 2; ++nf2)
#pragma unroll
      for (int ks = 0; ks < 2; ++ks) {
        int row = (half * 2 + nf2) * 16 + lr;
        bfrg[nf2][ks] = *(const short8*)&Wb[row * 64 + (((ks * 4 + lg) ^ (lr & 7)) * 8)];
      }
#pragma unroll
    for (int mf = 0; mf < 4; ++mf)
#pragma unroll
      for (int ks = 0; ks < 2; ++ks) {
        short8 af = *(const short8*)&Cy[kt * 4096 + (mf * 16 + lr) * 64 + (((ks * 4 + lg) ^ (lr & 7)) * 8)];
#pragma unroll
        for (int nf2 = 0; nf2 < 2; ++nf2) {
          if (s < 4)
            aK[mf][nf2] = __builtin_amdgcn_mfma_f32_16x16x32_bf16(af, bfrg[nf2][ks], aK[mf][nf2], 0, 0, 0);
          else
            aV[mf][nf2] = __builtin_amdgcn_mfma_f32_16x16x32_bf16(af, bfrg[nf2][ks], aV[mf][nf2], 0, 0, 0);
        }
      }
  }

  const unsigned short* qb = qwin + (size_t)((bb * 8 + head) * 64 + win) * 3136;
  short8 qf[2][2];
#pragma unroll
  for (int mf2 = 0; mf2 < 2; ++mf2)
#pragma unroll
    for (int ks = 0; ks < 2; ++ks)
      qf[mf2][ks] = *(const short8*)&qb[((half * 2 + mf2) * 16 + lr) * 64 + ks * 32 + lg * 8];

  BARRIER();  // (2) staged Wkv fully consumed -> overwrite with K/V

#pragma unroll
  for (int mf = 0; mf < 4; ++mf)
#pragma unroll
    for (int nf2 = 0; nf2 < 2; ++nf2) {
      int d = (half * 2 + nf2) * 16 + lr;
#pragma unroll
      for (int r = 0; r < 4; ++r) {
        int key = mf * 16 + lg * 4 + r;
        SLh[key * 64 + (((d >> 3) ^ (key & 7)) * 8) + (d & 7)] = f2bf(aK[mf][nf2][r]);
      }
      int slotv = (mf * 2 + (lg >> 1)) ^ (d & 7);
      ushort4v pv = { f2bf(aV[mf][nf2][0]), f2bf(aV[mf][nf2][1]),
                      f2bf(aV[mf][nf2][2]), f2bf(aV[mf][nf2][3]) };
      *(ushort4v*)&SLh[4096 + d * 64 + slotv * 8 + (lg & 1) * 4] = pv;
    }
  asm volatile("s_waitcnt lgkmcnt(0)" ::: "memory");
  BARRIER();  // (3) K & V^T complete

  f32x4 aS[2][4];
#pragma unroll
  for (int i = 0; i < 2; ++i)
#pragma unroll
    for (int j = 0; j < 4; ++j) aS[i][j] = (f32x4){0,0,0,0};
#pragma unroll
  for (int mf2 = 0; mf2 < 2; ++mf2)
#pragma unroll
    for (int ks = 0; ks < 2; ++ks)
#pragma unroll
      for (int nf = 0; nf < 4; ++nf) {
        short8 bk = *(const short8*)&SLh[(nf * 16 + lr) * 64 + (((ks * 4 + lg) ^ (lr & 7)) * 8)];
        aS[mf2][nf] = __builtin_amdgcn_mfma_f32_16x16x32_bf16(qf[mf2][ks], bk, aS[mf2][nf], 0, 0, 0);
      }

#pragma unroll
  for (int nf = 0; nf < 4; ++nf)
    if (nf * 16 + lr >= 49) {
#pragma unroll
      for (int mf2 = 0; mf2 < 2; ++mf2)
#pragma unroll
        for (int r = 0; r < 4; ++r) aS[mf2][nf][r] = -1e30f;
    }
  const float cexp = 0.125f * 1.4426950408889634f;
  float mx[2][4], sm[2][4];
#pragma unroll
  for (int mf2 = 0; mf2 < 2; ++mf2)
#pragma unroll
    for (int r = 0; r < 4; ++r)
      mx[mf2][r] = fmaxf(fmaxf(aS[mf2][0][r], aS[mf2][1][r]), fmaxf(aS[mf2][2][r], aS[mf2][3][r]));
#pragma unroll
  for (int m = 1; m <= 8; m <<= 1)
#pragma unroll
    for (int mf2 = 0; mf2 < 2; ++mf2)
#pragma unroll
      for (int r = 0; r < 4; ++r) mx[mf2][r] = fmaxf(mx[mf2][r], __shfl_xor(mx[mf2][r], m));
#pragma unroll
  for (int mf2 = 0; mf2 < 2; ++mf2)
#pragma unroll
    for (int nf = 0; nf < 4; ++nf)
#pragma unroll
      for (int r = 0; r < 4; ++r)
        aS[mf2][nf][r] = exp2f((aS[mf2][nf][r] - mx[mf2][r]) * cexp);
#pragma unroll
  for (int mf2 = 0; mf2 < 2; ++mf2)
#pragma unroll
    for (int r = 0; r < 4; ++r)
      sm[mf2][r] = aS[mf2][0][r] + aS[mf2][1][r] + aS[mf2][2][r] + aS[mf2][3][r];
#pragma unroll
  for (int m = 1; m <= 8; m <<= 1)
#pragma unroll
    for (int mf2 = 0; mf2 < 2; ++mf2)
#pragma unroll
      for (int r = 0; r < 4; ++r) sm[mf2][r] += __shfl_xor(sm[mf2][r], m);
#pragma unroll
  for (int mf2 = 0; mf2 < 2; ++mf2)
#pragma unroll
    for (int r = 0; r < 4; ++r) sm[mf2][r] = 1.f / sm[mf2][r];

  BARRIER();  // (4) K reads done -> overwrite buf0 with P

#pragma unroll
  for (int mf2 = 0; mf2 < 2; ++mf2)
#pragma unroll
    for (int nf = 0; nf < 4; ++nf)
#pragma unroll
      for (int r = 0; r < 4; ++r) {
        int q = (half * 2 + mf2) * 16 + lg * 4 + r;
        int key = nf * 16 + lr;
        SLh[q * 64 + (((key >> 3) ^ (q & 7)) * 8) + (key & 7)] = f2bf(aS[mf2][nf][r] * sm[mf2][r]);
      }

  f32x4 aO[2][4];
#pragma unroll
  for (int i = 0; i < 2; ++i)
#pragma unroll
    for (int j = 0; j < 4; ++j) aO[i][j] = (f32x4){0,0,0,0};
#pragma unroll
  for (int mf2 = 0; mf2 < 2; ++mf2)
#pragma unroll
    for (int ks = 0; ks < 2; ++ks) {
      int qrow = (half * 2 + mf2) * 16 + lr;
      short8 pf = *(const short8*)&SLh[qrow * 64 + (((ks * 4 + lg) ^ (lr & 7)) * 8)];
#pragma unroll
      for (int df = 0; df < 4; ++df) {
        short8 vf = *(const short8*)&SLh[4096 + (df * 16 + lr) * 64 + (((ks * 4 + lg) ^ (lr & 7)) * 8)];
        aO[mf2][df] = __builtin_amdgcn_mfma_f32_16x16x32_bf16(pf, vf, aO[mf2][df], 0, 0, 0);
      }
    }

  BARRIER();  // (5) PV done -> SL regions reusable as OA / WP

#pragma unroll
  for (int mf2 = 0; mf2 < 2; ++mf2)
#pragma unroll
    for (int df = 0; df < 4; ++df)
#pragma unroll
      for (int r = 0; r < 4; ++r) {
        int q = (half * 2 + mf2) * 16 + lg * 4 + r;
        int slot = df * 2 + (lr >> 3);
        OA[q * 512 + head * 64 + ((slot ^ (q & 7)) * 8) + (lr & 7)] = f2bf(aO[mf2][df][r]);
      }
#pragma unroll
  for (int c = 0; c < 4; ++c) {
    int lrow = c * 8 + r8;
    GLOAD16(Wproj_b + (size_t)(head * 64 + half * 32 + lrow) * 512 + ((sl8 ^ r8) * 8),
            &WPs[c * 512]);
  }
  asm volatile("s_waitcnt lgkmcnt(0) vmcnt(0)" ::: "memory");
  BARRIER();  // (6) OA + WP(0) ready

  f32x4 aR[4][2];
#pragma unroll
  for (int i = 0; i < 4; ++i)
#pragma unroll
    for (int j = 0; j < 2; ++j) aR[i][j] = (f32x4){0,0,0,0};
#pragma unroll
  for (int kt = 0; kt < 8; ++kt) {
    short8 nx[4];
    if (kt < 7) {
#pragma unroll
      for (int c = 0; c < 4; ++c) {
        int lrow = c * 8 + r8;
        nx[c] = *(const short8*)&Wproj_b[(size_t)(head * 64 + half * 32 + lrow) * 512
                                         + (kt + 1) * 64 + ((sl8 ^ r8) * 8)];
      }
    }
#pragma unroll
    for (int mf = 0; mf < 4; ++mf)
#pragma unroll
      for (int ks = 0; ks < 2; ++ks) {
        short8 af2 = *(const short8*)&OA[(mf * 16 + lr) * 512 + kt * 64 + (((ks * 4 + lg) ^ (lr & 7)) * 8)];
#pragma unroll
        for (int nf2 = 0; nf2 < 2; ++nf2) {
          short8 bf2 = *(const short8*)&WPs[(nf2 * 16 + lr) * 64 + (((ks * 4 + lg) ^ (lr & 7)) * 8)];
          aR[mf][nf2] = __builtin_amdgcn_mfma_f32_16x16x32_bf16(af2, bf2, aR[mf][nf2], 0, 0, 0);
        }
      }
    if (kt < 7) {
#pragma unroll
      for (int c = 0; c < 4; ++c)
        *(short8*)&WPs[(c * 8 + r8) * 64 + sl8 * 8] = nx[c];
    }
  }

#pragma unroll
  for (int mf = 0; mf < 4; ++mf)
#pragma unroll
    for (int nf2 = 0; nf2 < 2; ++nf2)
#pragma unroll
      for (int r = 0; r < 4; ++r) {
        int q = mf * 16 + lg * 4 + r;
        if (q < 49) {
          int gm = bb * 3136 + (ht * 7 + q / 7) * 56 + wt * 7 + (q % 7);
          int col = head * 64 + (half * 2 + nf2) * 16 + lr;
          out[(size_t)gm * 512 + col] = aR[mf][nf2][r] + bproj[col];
        }
      }
}

// ---------- launcher ----------
extern "C" void kernel_launch(void* const* d_in, const int* in_sizes, int n_in,
                              void* d_out, int out_size, void* d_ws, size_t ws_size,
                              hipStream_t stream) {
  const float* x     = (const float*)d_in[0];
  const float* y     = (const float*)d_in[1];
  const float* Wq    = (const float*)d_in[2];
  const float* Wkv   = (const float*)d_in[3];
  const float* Wproj = (const float*)d_in[4];
  const float* bproj = (const float*)d_in[5];
  const float* Wsr   = (const float*)d_in[6];
  const float* bsr   = (const float*)d_in[7];
  const float* gn    = (const float*)d_in[8];
  const float* bn    = (const float*)d_in[9];
  float* out = (float*)d_out;

  char* ws = (char*)d_ws;
  unsigned short* Wq_b    = (unsigned short*)ws; ws += 524288;
  unsigned short* Wkv_b   = (unsigned short*)ws; ws += 524288;
  unsigned short* Wproj_b = (unsigned short*)ws; ws += 524288;
  unsigned short* Wsr_b   = (unsigned short*)ws; ws += 131072;
  unsigned short* regA    = (unsigned short*)ws; ws += 12845056; // pooled bf16
  unsigned short* q_win   = (unsigned short*)ws; ws += 25690112; // q windows
  unsigned short* regC    = (unsigned short*)ws; ws += 12845056; // y2 bf16

  // weight converts (unblocks everything quickly)
  wcvt<<<832, 256, 0, stream>>>(Wq, Wkv, Wproj, Wsr, Wq_b, Wkv_b, Wproj_b, Wsr_b);

  // co-dispatched: q-proj GEMM (196 blocks, compute) + avgpool (3136 blocks, HBM)
  qpool<<<3332, 512, 0, stream>>>(x, Wq_b, q_win, y, regA);

  // fused conv+bias+LN+GELU -> y2
  sr_gemm<<<392, 256, 0, stream>>>(regA, Wsr_b, bsr, gn, bn, regC);

  // mega-fused kv-proj + attention + out-proj -> f32 d_out
  kvattn<<<512, 1024, 0, stream>>>(regC, Wkv_b, q_win, Wproj_b, bproj, out);
}

// Round 17
// 138.121 us; speedup vs baseline: 1.0038x; 1.0038x over previous
//
#include <hip/hip_runtime.h>
#include <hip/hip_bf16.h>

// ---------- common ----------
typedef __attribute__((ext_vector_type(8))) short short8;
typedef __attribute__((ext_vector_type(4))) float f32x4;
typedef __attribute__((ext_vector_type(4))) unsigned short ushort4v;

#define DI __device__ __forceinline__

DI unsigned short f2bf(float f) {
  union { float f; unsigned int u; } a; a.f = f;
  unsigned int u = a.u;
  return (unsigned short)((u + 0x7FFFu + ((u >> 16) & 1u)) >> 16);
}

#define BARRIER() do { asm volatile("" ::: "memory"); __builtin_amdgcn_s_barrier(); asm volatile("" ::: "memory"); } while (0)
#define GLOAD16(src, dst) __builtin_amdgcn_global_load_lds( \
    (const __attribute__((address_space(1))) void*)(src), \
    (__attribute__((address_space(3))) void*)(dst), 16, 0, 0)

// Problem: B=8, H1=W1=56, N1=3136, C1=512, C2=256, NH=8, HD=64, WS=7, M=25088

// ---------- merged: 2x2 avgpool(+cvt) for y | weight f32->bf16 converts ----------
__global__ __launch_bounds__(256)
void cvt_pool(const float* __restrict__ y, unsigned short* __restrict__ pooled,
              const float* __restrict__ Wq, const float* __restrict__ Wkv,
              const float* __restrict__ Wproj, const float* __restrict__ Wsr,
              unsigned short* __restrict__ Wq_b, unsigned short* __restrict__ Wkv_b,
              unsigned short* __restrict__ Wproj_b, unsigned short* __restrict__ Wsr_b) {
  int bid = blockIdx.x;
  if (bid < 6272) {
    int t = bid * 256 + threadIdx.x;
    int cv = (t & 63) * 4;
    int bp = t >> 6;
    int b = bp / 3136, p = bp % 3136;
    int hp = p / 56, wp = p % 56;
    const float* src = y + (((size_t)b * 12544) + hp * 224 + wp * 2) * 256 + cv;
    float4 a0 = *(const float4*)(src);
    float4 a1 = *(const float4*)(src + 256);
    float4 a2 = *(const float4*)(src + 28672);
    float4 a3 = *(const float4*)(src + 28672 + 256);
    float4 av;
    av.x = (a0.x + a1.x + a2.x + a3.x) * 0.25f;
    av.y = (a0.y + a1.y + a2.y + a3.y) * 0.25f;
    av.z = (a0.z + a1.z + a2.z + a3.z) * 0.25f;
    av.w = (a0.w + a1.w + a2.w + a3.w) * 0.25f;
    ushort4v o = { f2bf(av.x), f2bf(av.y), f2bf(av.z), f2bf(av.w) };
    *(ushort4v*)&pooled[(size_t)bp * 256 + cv] = o;
  } else {
    long i = (long)(bid - 6272) * 1024 + threadIdx.x * 4;
    const float* src; unsigned short* dst; long off;
    if (i < 262144L)      { src = Wq;    dst = Wq_b;    off = i; }
    else if (i < 524288L) { src = Wkv;   dst = Wkv_b;   off = i - 262144L; }
    else if (i < 786432L) { src = Wproj; dst = Wproj_b; off = i - 524288L; }
    else                  { src = Wsr;   dst = Wsr_b;   off = i - 786432L; }
    float4 v = *(const float4*)&src[off];
    ushort4v o = { f2bf(v.x), f2bf(v.y), f2bf(v.z), f2bf(v.w) };
    *(ushort4v*)&dst[off] = o;
  }
}

// ---------- q-window scatter epilogue ----------
DI void epi_q(int gm, int gc, float v, unsigned short* outp) {
  const int b = gm / 3136, pos = gm % 3136;
  const int h = pos / 56, ww = pos % 56;
  const int head = gc >> 6, d = gc & 63;
  const size_t idx = ((((size_t)(b * 8 + head)) * 64 + (h / 7) * 8 + (ww / 7)) * 49
                      + (h % 7) * 7 + (ww % 7)) * 64 + d;
  outp[idx] = f2bf(v);
}

// ---------- merged dispatch: q-proj GEMM (blocks 0..195) | sr conv+LN+GELU (196..391) ----------
// Both compute-phase; co-scheduling fills idle CUs. (Do NOT co-dispatch the pool here:
// its 103MB HBM stream congests the GEMM's latency-sensitive pipeline — measured R16.)
__global__ __launch_bounds__(512, 2)
void qsr_gemm(const float* __restrict__ A,            // x (f32)
              const unsigned short* __restrict__ Bw,  // Wq_b
              unsigned short* __restrict__ outp,      // q_win
              const unsigned short* __restrict__ Ap,  // pooled bf16
              const unsigned short* __restrict__ Wsr_b,
              const float* __restrict__ bsr, const float* __restrict__ gn,
              const float* __restrict__ bn, unsigned short* __restrict__ y2out) {
  __shared__ unsigned short lds[65536];
  const int bid = blockIdx.x;
  const int tid = threadIdx.x;
  const int wv = tid >> 6;
  const int lane = tid & 63;
  const int lr = lane & 15;
  const int lg = lane >> 4;
  const int lr4 = lg * 4;
  const int srow8 = lane >> 3;
  const int sl8 = lane & 7;

  if (bid < 196) {
    const int wm = wv >> 2;
    const int wn = wv & 3;
    const int m0 = (bid >> 1) * 256;
    const int n0 = (bid & 1) * 256;
    constexpr int K = 512, NT = K / 64;

    f32x4 acc[8][4];
#pragma unroll
    for (int i = 0; i < 8; ++i)
#pragma unroll
      for (int j = 0; j < 4; ++j) acc[i][j] = (f32x4){0.f, 0.f, 0.f, 0.f};

    float4 fa[4][2];
    auto loadA = [&](int t1) {
      int tsrc = (t1 < NT) ? t1 : NT - 1;
#pragma unroll
      for (int rr = 0; rr < 4; ++rr) {
        int trow = rr * 64 + wv * 8 + srow8;
        const float* p = A + (size_t)(m0 + trow) * K + tsrc * 64 + sl8 * 8;
        fa[rr][0] = *(const float4*)p;
        fa[rr][1] = *(const float4*)(p + 4);
      }
      asm volatile("" ::: "memory");
    };
    auto writeA = [&](int t1) {
#pragma unroll
      for (int rr = 0; rr < 4; ++rr) {
        int trow = rr * 64 + wv * 8 + srow8;
        union { short8 s; unsigned short u[8]; } w;
        w.u[0] = f2bf(fa[rr][0].x); w.u[1] = f2bf(fa[rr][0].y);
        w.u[2] = f2bf(fa[rr][0].z); w.u[3] = f2bf(fa[rr][0].w);
        w.u[4] = f2bf(fa[rr][1].x); w.u[5] = f2bf(fa[rr][1].y);
        w.u[6] = f2bf(fa[rr][1].z); w.u[7] = f2bf(fa[rr][1].w);
        *(short8*)&lds[(t1 & 1) * 32768 + trow * 64 + ((sl8 ^ (trow & 7)) * 8)] = w.s;
      }
    };
    auto stageB = [&](int t1, int rr) {
      int tsrc = (t1 < NT) ? t1 : NT - 1;
      int trow = rr * 64 + wv * 8 + srow8;
      int sx = sl8 ^ (trow & 7);
      GLOAD16(Bw + (size_t)(n0 + trow) * K + tsrc * 64 + sx * 8,
              &lds[(t1 & 1) * 32768 + 16384 + (rr * 64 + wv * 8) * 64]);
    };
    auto rdA = [&](int s, int mf, int ks) -> short8 {
      int row = wm * 128 + mf * 16 + lr;
      int slot = ((ks << 2) + lg) ^ (row & 7);
      return *(const short8*)&lds[s * 32768 + row * 64 + slot * 8];
    };
    auto rdB = [&](int s, int nf, int ks) -> short8 {
      int row = wn * 64 + nf * 16 + lr;
      int slot = ((ks << 2) + lg) ^ (row & 7);
      return *(const short8*)&lds[s * 32768 + 16384 + row * 64 + slot * 8];
    };

    stageB(0, 0); stageB(0, 1); stageB(0, 2); stageB(0, 3);
    loadA(0);
    asm volatile("s_waitcnt vmcnt(0)" ::: "memory");
    writeA(0);
    asm volatile("s_waitcnt lgkmcnt(0)" ::: "memory");
    BARRIER();

    for (int t = 0; t < NT; ++t) {
      const int s = t & 1;
      short8 bfr[4][2];
      loadA(t + 1);
#pragma unroll
      for (int j = 0; j < 4; ++j) { bfr[j][0] = rdB(s, j, 0); bfr[j][1] = rdB(s, j, 1); }
      {
        short8 x0 = rdA(s, 0, 0), x1 = rdA(s, 0, 1);
        short8 y0 = rdA(s, 1, 0), y1 = rdA(s, 1, 1);
        BARRIER();
        __builtin_amdgcn_s_setprio(1);
#pragma unroll
        for (int j = 0; j < 4; ++j) {
          acc[0][j] = __builtin_amdgcn_mfma_f32_16x16x32_bf16(x0, bfr[j][0], acc[0][j], 0, 0, 0);
          acc[0][j] = __builtin_amdgcn_mfma_f32_16x16x32_bf16(x1, bfr[j][1], acc[0][j], 0, 0, 0);
          acc[1][j] = __builtin_amdgcn_mfma_f32_16x16x32_bf16(y0, bfr[j][0], acc[1][j], 0, 0, 0);
          acc[1][j] = __builtin_amdgcn_mfma_f32_16x16x32_bf16(y1, bfr[j][1], acc[1][j], 0, 0, 0);
        }
        __builtin_amdgcn_s_setprio(0);
        BARRIER();
      }
      stageB(t + 1, 0); stageB(t + 1, 1);
      {
        short8 x0 = rdA(s, 2, 0), x1 = rdA(s, 2, 1);
        short8 y0 = rdA(s, 3, 0), y1 = rdA(s, 3, 1);
        BARRIER();
        __builtin_amdgcn_s_setprio(1);
#pragma unroll
        for (int j = 0; j < 4; ++j) {
          acc[2][j] = __builtin_amdgcn_mfma_f32_16x16x32_bf16(x0, bfr[j][0], acc[2][j], 0, 0, 0);
          acc[2][j] = __builtin_amdgcn_mfma_f32_16x16x32_bf16(x1, bfr[j][1], acc[2][j], 0, 0, 0);
          acc[3][j] = __builtin_amdgcn_mfma_f32_16x16x32_bf16(y0, bfr[j][0], acc[3][j], 0, 0, 0);
          acc[3][j] = __builtin_amdgcn_mfma_f32_16x16x32_bf16(y1, bfr[j][1], acc[3][j], 0, 0, 0);
        }
        __builtin_amdgcn_s_setprio(0);
        BARRIER();
      }
      stageB(t + 1, 2); stageB(t + 1, 3);
      {
        short8 x0 = rdA(s, 4, 0), x1 = rdA(s, 4, 1);
        short8 y0 = rdA(s, 5, 0), y1 = rdA(s, 5, 1);
        BARRIER();
        __builtin_amdgcn_s_setprio(1);
#pragma unroll
        for (int j = 0; j < 4; ++j) {
          acc[4][j] = __builtin_amdgcn_mfma_f32_16x16x32_bf16(x0, bfr[j][0], acc[4][j], 0, 0, 0);
          acc[4][j] = __builtin_amdgcn_mfma_f32_16x16x32_bf16(x1, bfr[j][1], acc[4][j], 0, 0, 0);
          acc[5][j] = __builtin_amdgcn_mfma_f32_16x16x32_bf16(y0, bfr[j][0], acc[5][j], 0, 0, 0);
          acc[5][j] = __builtin_amdgcn_mfma_f32_16x16x32_bf16(y1, bfr[j][1], acc[5][j], 0, 0, 0);
        }
        __builtin_amdgcn_s_setprio(0);
        BARRIER();
      }
      {
        short8 x0 = rdA(s, 6, 0), x1 = rdA(s, 6, 1);
        short8 y0 = rdA(s, 7, 0), y1 = rdA(s, 7, 1);
        asm volatile("s_waitcnt vmcnt(4)" ::: "memory");
        writeA(t + 1);
        asm volatile("s_waitcnt lgkmcnt(0)" ::: "memory");
        BARRIER();
        __builtin_amdgcn_s_setprio(1);
#pragma unroll
        for (int j = 0; j < 4; ++j) {
          acc[6][j] = __builtin_amdgcn_mfma_f32_16x16x32_bf16(x0, bfr[j][0], acc[6][j], 0, 0, 0);
          acc[6][j] = __builtin_amdgcn_mfma_f32_16x16x32_bf16(x1, bfr[j][1], acc[6][j], 0, 0, 0);
          acc[7][j] = __builtin_amdgcn_mfma_f32_16x16x32_bf16(y0, bfr[j][0], acc[7][j], 0, 0, 0);
          acc[7][j] = __builtin_amdgcn_mfma_f32_16x16x32_bf16(y1, bfr[j][1], acc[7][j], 0, 0, 0);
        }
        __builtin_amdgcn_s_setprio(0);
        asm volatile("s_waitcnt vmcnt(0)" ::: "memory");
        BARRIER();
      }
    }

#pragma unroll
    for (int i = 0; i < 8; ++i)
#pragma unroll
      for (int j = 0; j < 4; ++j)
#pragma unroll
        for (int r = 0; r < 4; ++r)
          epi_q(m0 + wm * 128 + i * 16 + lr4 + r, n0 + wn * 64 + j * 16 + lr,
                acc[i][j][r], outp);
  } else {
    // ---- sr: conv GEMM + bias + LN + GELU, 128 rows/block, shared Wsr B-tile ----
    unsigned short* sA = lds;                    // [128][64]
    unsigned short* sB = lds + 8192;             // [256][64]
    float* red = (float*)&lds[24576];            // [2][64][8]
    const int tl = wv >> 2;
    const int w4 = wv & 3;
    const int m0 = (bid - 196) * 128;

    f32x4 acc[4][4];
#pragma unroll
    for (int i = 0; i < 4; ++i)
#pragma unroll
      for (int j = 0; j < 4; ++j) acc[i][j] = (f32x4){0.f, 0.f, 0.f, 0.f};

    for (int kt = 0; kt < 256; kt += 64) {
#pragma unroll
      for (int c = 0; c < 2; ++c) {
        int row = tl * 64 + w4 * 16 + c * 8 + srow8;
        GLOAD16(Ap + (size_t)(m0 + row) * 256 + kt + ((sl8 ^ srow8) * 8),
                &sA[row * 64]);
      }
#pragma unroll
      for (int c = 0; c < 4; ++c) {
        int row = wv * 32 + c * 8 + srow8;
        GLOAD16(Wsr_b + (size_t)row * 256 + kt + ((sl8 ^ srow8) * 8),
                &sB[row * 64]);
      }
      __syncthreads();
#pragma unroll
      for (int ks = 0; ks < 2; ++ks) {
        short8 af[4], bfr[4];
#pragma unroll
        for (int i = 0; i < 4; ++i)
          af[i] = *(const short8*)&sA[(tl * 64 + i * 16 + lr) * 64 + (((ks * 4 + lg) ^ (lr & 7)) * 8)];
#pragma unroll
        for (int j = 0; j < 4; ++j)
          bfr[j] = *(const short8*)&sB[(w4 * 64 + j * 16 + lr) * 64 + (((ks * 4 + lg) ^ (lr & 7)) * 8)];
#pragma unroll
        for (int i = 0; i < 4; ++i)
#pragma unroll
          for (int j = 0; j < 4; ++j)
            acc[i][j] = __builtin_amdgcn_mfma_f32_16x16x32_bf16(af[i], bfr[j], acc[i][j], 0, 0, 0);
      }
      __syncthreads();
    }

    float bsv[4], gnv[4], bnv[4];
#pragma unroll
    for (int j = 0; j < 4; ++j) {
      int col = w4 * 64 + j * 16 + lr;
      bsv[j] = bsr[col]; gnv[j] = gn[col]; bnv[j] = bn[col];
    }
    float s_[4][4], q_[4][4];
#pragma unroll
    for (int i = 0; i < 4; ++i)
#pragma unroll
      for (int r = 0; r < 4; ++r) {
        float s = 0.f, q = 0.f;
#pragma unroll
        for (int j = 0; j < 4; ++j) {
          float v = acc[i][j][r] + bsv[j];
          acc[i][j][r] = v;
          s += v; q += v * v;
        }
        s_[i][r] = s; q_[i][r] = q;
      }
#pragma unroll
    for (int m = 1; m <= 8; m <<= 1)
#pragma unroll
      for (int i = 0; i < 4; ++i)
#pragma unroll
        for (int r = 0; r < 4; ++r) {
          s_[i][r] += __shfl_xor(s_[i][r], m);
          q_[i][r] += __shfl_xor(q_[i][r], m);
        }
    if (lr == 0) {
#pragma unroll
      for (int i = 0; i < 4; ++i)
#pragma unroll
        for (int r = 0; r < 4; ++r) {
          int row = i * 16 + lr4 + r;
          red[(tl * 64 + row) * 8 + w4 * 2 + 0] = s_[i][r];
          red[(tl * 64 + row) * 8 + w4 * 2 + 1] = q_[i][r];
        }
    }
    __syncthreads();
#pragma unroll
    for (int i = 0; i < 4; ++i) {
#pragma unroll
      for (int r = 0; r < 4; ++r) {
        int row = i * 16 + lr4 + r;
        const float* rd = &red[(tl * 64 + row) * 8];
        float sum = rd[0] + rd[2] + rd[4] + rd[6];
        float sq  = rd[1] + rd[3] + rd[5] + rd[7];
        float mean = sum * (1.f / 256.f);
        float var = sq * (1.f / 256.f) - mean * mean;
        float rstd = rsqrtf(var + 1e-5f);
#pragma unroll
        for (int j = 0; j < 4; ++j) {
          float t = (acc[i][j][r] - mean) * rstd * gnv[j] + bnv[j];
          t = 0.5f * t * (1.f + erff(t * 0.70710678118654752f));
          y2out[(size_t)(m0 + tl * 64 + row) * 256 + w4 * 64 + j * 16 + lr] = f2bf(t);
        }
      }
    }
  }
}

// ---------- mega-fused kv-proj + attention + out-proj: 16 waves = 8 heads x 2 halves ----------
// R8 structure (h2-major Wkv staging — do not reorder; kt-major thrashes L2, +46MB FETCH).
// V^T writes packed to b64.
__global__ __launch_bounds__(1024)
void kvattn(const unsigned short* __restrict__ y2,
            const unsigned short* __restrict__ Wkv_b,
            const unsigned short* __restrict__ qwin,
            const unsigned short* __restrict__ Wproj_b,
            const float* __restrict__ bproj,
            float* __restrict__ out) {
  __shared__ unsigned short lds[81920];
  const int tid = threadIdx.x;
  const int wv16 = tid >> 6;
  const int head = wv16 >> 1;
  const int half = wv16 & 1;
  const int lane = tid & 63;
  const int lr = lane & 15;
  const int lg = lane >> 4;
  const int r8 = lane >> 3;
  const int sl8 = lane & 7;
  const int bb = blockIdx.x >> 6;
  const int win = blockIdx.x & 63;
  const int ht = win >> 3, wt = win & 7;

  unsigned short* Cy  = lds;
  unsigned short* SLh = lds + 16384 + head * 8192;
  unsigned short* OA  = lds + 16384;
  unsigned short* WPs = lds + 49152 + wv16 * 2048;

  {
    int rb = wv16 & 7;
    int m = rb * 8 + r8;
    int mm = (m < 49) ? m : 48;
    int grow = bb * 3136 + (ht * 7 + mm / 7) * 56 + wt * 7 + (mm % 7);
    int p0 = wv16 >> 3;
#pragma unroll
    for (int pp = 0; pp < 2; ++pp) {
      int panel = p0 + pp * 2;
      GLOAD16(y2 + (size_t)grow * 256 + panel * 64 + ((sl8 ^ (m & 7)) * 8),
              &Cy[panel * 4096 + rb * 512]);
    }
  }

  auto stageW = [&](int s) {  // h2-major: h2 = s>>2, kt = s&3
    int h2 = s >> 2, kt = s & 3;
#pragma unroll
    for (int c = 0; c < 4; ++c) {
      int lrow = half * 32 + c * 8 + r8;
      GLOAD16(Wkv_b + (size_t)(h2 * 512 + head * 64 + lrow) * 256 + kt * 64 + ((sl8 ^ r8) * 8),
              &SLh[(s & 1) * 4096 + (half * 32 + c * 8) * 64]);
    }
  };

  f32x4 aK[4][2], aV[4][2];
#pragma unroll
  for (int i = 0; i < 4; ++i)
#pragma unroll
    for (int j = 0; j < 2; ++j) { aK[i][j] = (f32x4){0,0,0,0}; aV[i][j] = (f32x4){0,0,0,0}; }

  stageW(0);
  asm volatile("s_waitcnt vmcnt(4)" ::: "memory");
  BARRIER();  // (1) Cy visible

#pragma unroll
  for (int s = 0; s < 8; ++s) {
    if (s < 7) {
      stageW(s + 1);
      asm volatile("s_waitcnt vmcnt(4)" ::: "memory");
    } else {
      asm volatile("s_waitcnt vmcnt(0)" ::: "memory");
    }
    const int kt = s & 3;
    const unsigned short* Wb = &SLh[(s & 1) * 4096];
    short8 bfrg[2][2];
#pragma unroll
    for (int nf2 = 0; nf2 < 2; ++nf2)
#pragma unroll
      for (int ks = 0; ks < 2; ++ks) {
        int row = (half * 2 + nf2) * 16 + lr;
        bfrg[nf2][ks] = *(const short8*)&Wb[row * 64 + (((ks * 4 + lg) ^ (lr & 7)) * 8)];
      }
#pragma unroll
    for (int mf = 0; mf < 4; ++mf)
#pragma unroll
      for (int ks = 0; ks < 2; ++ks) {
        short8 af = *(const short8*)&Cy[kt * 4096 + (mf * 16 + lr) * 64 + (((ks * 4 + lg) ^ (lr & 7)) * 8)];
#pragma unroll
        for (int nf2 = 0; nf2 < 2; ++nf2) {
          if (s < 4)
            aK[mf][nf2] = __builtin_amdgcn_mfma_f32_16x16x32_bf16(af, bfrg[nf2][ks], aK[mf][nf2], 0, 0, 0);
          else
            aV[mf][nf2] = __builtin_amdgcn_mfma_f32_16x16x32_bf16(af, bfrg[nf2][ks], aV[mf][nf2], 0, 0, 0);
        }
      }
  }

  const unsigned short* qb = qwin + (size_t)((bb * 8 + head) * 64 + win) * 3136;
  short8 qf[2][2];
#pragma unroll
  for (int mf2 = 0; mf2 < 2; ++mf2)
#pragma unroll
    for (int ks = 0; ks < 2; ++ks)
      qf[mf2][ks] = *(const short8*)&qb[((half * 2 + mf2) * 16 + lr) * 64 + ks * 32 + lg * 8];

  BARRIER();  // (2) staged Wkv fully consumed -> overwrite with K/V

#pragma unroll
  for (int mf = 0; mf < 4; ++mf)
#pragma unroll
    for (int nf2 = 0; nf2 < 2; ++nf2) {
      int d = (half * 2 + nf2) * 16 + lr;
#pragma unroll
      for (int r = 0; r < 4; ++r) {
        int key = mf * 16 + lg * 4 + r;
        SLh[key * 64 + (((d >> 3) ^ (key & 7)) * 8) + (d & 7)] = f2bf(aK[mf][nf2][r]);
      }
      int slotv = (mf * 2 + (lg >> 1)) ^ (d & 7);
      ushort4v pv = { f2bf(aV[mf][nf2][0]), f2bf(aV[mf][nf2][1]),
                      f2bf(aV[mf][nf2][2]), f2bf(aV[mf][nf2][3]) };
      *(ushort4v*)&SLh[4096 + d * 64 + slotv * 8 + (lg & 1) * 4] = pv;
    }
  asm volatile("s_waitcnt lgkmcnt(0)" ::: "memory");
  BARRIER();  // (3) K & V^T complete

  f32x4 aS[2][4];
#pragma unroll
  for (int i = 0; i < 2; ++i)
#pragma unroll
    for (int j = 0; j < 4; ++j) aS[i][j] = (f32x4){0,0,0,0};
#pragma unroll
  for (int mf2 = 0; mf2 < 2; ++mf2)
#pragma unroll
    for (int ks = 0; ks < 2; ++ks)
#pragma unroll
      for (int nf = 0; nf < 4; ++nf) {
        short8 bk = *(const short8*)&SLh[(nf * 16 + lr) * 64 + (((ks * 4 + lg) ^ (lr & 7)) * 8)];
        aS[mf2][nf] = __builtin_amdgcn_mfma_f32_16x16x32_bf16(qf[mf2][ks], bk, aS[mf2][nf], 0, 0, 0);
      }

#pragma unroll
  for (int nf = 0; nf < 4; ++nf)
    if (nf * 16 + lr >= 49) {
#pragma unroll
      for (int mf2 = 0; mf2 < 2; ++mf2)
#pragma unroll
        for (int r = 0; r < 4; ++r) aS[mf2][nf][r] = -1e30f;
    }
  const float cexp = 0.125f * 1.4426950408889634f;
  float mx[2][4], sm[2][4];
#pragma unroll
  for (int mf2 = 0; mf2 < 2; ++mf2)
#pragma unroll
    for (int r = 0; r < 4; ++r)
      mx[mf2][r] = fmaxf(fmaxf(aS[mf2][0][r], aS[mf2][1][r]), fmaxf(aS[mf2][2][r], aS[mf2][3][r]));
#pragma unroll
  for (int m = 1; m <= 8; m <<= 1)
#pragma unroll
    for (int mf2 = 0; mf2 < 2; ++mf2)
#pragma unroll
      for (int r = 0; r < 4; ++r) mx[mf2][r] = fmaxf(mx[mf2][r], __shfl_xor(mx[mf2][r], m));
#pragma unroll
  for (int mf2 = 0; mf2 < 2; ++mf2)
#pragma unroll
    for (int nf = 0; nf < 4; ++nf)
#pragma unroll
      for (int r = 0; r < 4; ++r)
        aS[mf2][nf][r] = exp2f((aS[mf2][nf][r] - mx[mf2][r]) * cexp);
#pragma unroll
  for (int mf2 = 0; mf2 < 2; ++mf2)
#pragma unroll
    for (int r = 0; r < 4; ++r)
      sm[mf2][r] = aS[mf2][0][r] + aS[mf2][1][r] + aS[mf2][2][r] + aS[mf2][3][r];
#pragma unroll
  for (int m = 1; m <= 8; m <<= 1)
#pragma unroll
    for (int mf2 = 0; mf2 < 2; ++mf2)
#pragma unroll
      for (int r = 0; r < 4; ++r) sm[mf2][r] += __shfl_xor(sm[mf2][r], m);
#pragma unroll
  for (int mf2 = 0; mf2 < 2; ++mf2)
#pragma unroll
    for (int r = 0; r < 4; ++r) sm[mf2][r] = 1.f / sm[mf2][r];

  BARRIER();  // (4) K reads done -> overwrite buf0 with P

#pragma unroll
  for (int mf2 = 0; mf2 < 2; ++mf2)
#pragma unroll
    for (int nf = 0; nf < 4; ++nf)
#pragma unroll
      for (int r = 0; r < 4; ++r) {
        int q = (half * 2 + mf2) * 16 + lg * 4 + r;
        int key = nf * 16 + lr;
        SLh[q * 64 + (((key >> 3) ^ (q & 7)) * 8) + (key & 7)] = f2bf(aS[mf2][nf][r] * sm[mf2][r]);
      }

  f32x4 aO[2][4];
#pragma unroll
  for (int i = 0; i < 2; ++i)
#pragma unroll
    for (int j = 0; j < 4; ++j) aO[i][j] = (f32x4){0,0,0,0};
#pragma unroll
  for (int mf2 = 0; mf2 < 2; ++mf2)
#pragma unroll
    for (int ks = 0; ks < 2; ++ks) {
      int qrow = (half * 2 + mf2) * 16 + lr;
      short8 pf = *(const short8*)&SLh[qrow * 64 + (((ks * 4 + lg) ^ (lr & 7)) * 8)];
#pragma unroll
      for (int df = 0; df < 4; ++df) {
        short8 vf = *(const short8*)&SLh[4096 + (df * 16 + lr) * 64 + (((ks * 4 + lg) ^ (lr & 7)) * 8)];
        aO[mf2][df] = __builtin_amdgcn_mfma_f32_16x16x32_bf16(pf, vf, aO[mf2][df], 0, 0, 0);
      }
    }

  BARRIER();  // (5) PV done -> SL regions reusable as OA / WP

#pragma unroll
  for (int mf2 = 0; mf2 < 2; ++mf2)
#pragma unroll
    for (int df = 0; df < 4; ++df)
#pragma unroll
      for (int r = 0; r < 4; ++r) {
        int q = (half * 2 + mf2) * 16 + lg * 4 + r;
        int slot = df * 2 + (lr >> 3);
        OA[q * 512 + head * 64 + ((slot ^ (q & 7)) * 8) + (lr & 7)] = f2bf(aO[mf2][df][r]);
      }
#pragma unroll
  for (int c = 0; c < 4; ++c) {
    int lrow = c * 8 + r8;
    GLOAD16(Wproj_b + (size_t)(head * 64 + half * 32 + lrow) * 512 + ((sl8 ^ r8) * 8),
            &WPs[c * 512]);
  }
  asm volatile("s_waitcnt lgkmcnt(0) vmcnt(0)" ::: "memory");
  BARRIER();  // (6) OA + WP(0) ready

  f32x4 aR[4][2];
#pragma unroll
  for (int i = 0; i < 4; ++i)
#pragma unroll
    for (int j = 0; j < 2; ++j) aR[i][j] = (f32x4){0,0,0,0};
#pragma unroll
  for (int kt = 0; kt < 8; ++kt) {
    short8 nx[4];
    if (kt < 7) {
#pragma unroll
      for (int c = 0; c < 4; ++c) {
        int lrow = c * 8 + r8;
        nx[c] = *(const short8*)&Wproj_b[(size_t)(head * 64 + half * 32 + lrow) * 512
                                         + (kt + 1) * 64 + ((sl8 ^ r8) * 8)];
      }
    }
#pragma unroll
    for (int mf = 0; mf < 4; ++mf)
#pragma unroll
      for (int ks = 0; ks < 2; ++ks) {
        short8 af2 = *(const short8*)&OA[(mf * 16 + lr) * 512 + kt * 64 + (((ks * 4 + lg) ^ (lr & 7)) * 8)];
#pragma unroll
        for (int nf2 = 0; nf2 < 2; ++nf2) {
          short8 bf2 = *(const short8*)&WPs[(nf2 * 16 + lr) * 64 + (((ks * 4 + lg) ^ (lr & 7)) * 8)];
          aR[mf][nf2] = __builtin_amdgcn_mfma_f32_16x16x32_bf16(af2, bf2, aR[mf][nf2], 0, 0, 0);
        }
      }
    if (kt < 7) {
#pragma unroll
      for (int c = 0; c < 4; ++c)
        *(short8*)&WPs[(c * 8 + r8) * 64 + sl8 * 8] = nx[c];
    }
  }

#pragma unroll
  for (int mf = 0; mf < 4; ++mf)
#pragma unroll
    for (int nf2 = 0; nf2 < 2; ++nf2)
#pragma unroll
      for (int r = 0; r < 4; ++r) {
        int q = mf * 16 + lg * 4 + r;
        if (q < 49) {
          int gm = bb * 3136 + (ht * 7 + q / 7) * 56 + wt * 7 + (q % 7);
          int col = head * 64 + (half * 2 + nf2) * 16 + lr;
          out[(size_t)gm * 512 + col] = aR[mf][nf2][r] + bproj[col];
        }
      }
}

// ---------- launcher ----------
extern "C" void kernel_launch(void* const* d_in, const int* in_sizes, int n_in,
                              void* d_out, int out_size, void* d_ws, size_t ws_size,
                              hipStream_t stream) {
  const float* x     = (const float*)d_in[0];
  const float* y     = (const float*)d_in[1];
  const float* Wq    = (const float*)d_in[2];
  const float* Wkv   = (const float*)d_in[3];
  const float* Wproj = (const float*)d_in[4];
  const float* bproj = (const float*)d_in[5];
  const float* Wsr   = (const float*)d_in[6];
  const float* bsr   = (const float*)d_in[7];
  const float* gn    = (const float*)d_in[8];
  const float* bn    = (const float*)d_in[9];
  float* out = (float*)d_out;

  char* ws = (char*)d_ws;
  unsigned short* Wq_b    = (unsigned short*)ws; ws += 524288;
  unsigned short* Wkv_b   = (unsigned short*)ws; ws += 524288;
  unsigned short* Wproj_b = (unsigned short*)ws; ws += 524288;
  unsigned short* Wsr_b   = (unsigned short*)ws; ws += 131072;
  unsigned short* regA    = (unsigned short*)ws; ws += 12845056; // pooled bf16
  unsigned short* q_win   = (unsigned short*)ws; ws += 25690112; // q windows
  unsigned short* regC    = (unsigned short*)ws; ws += 12845056; // y2 bf16

  // pool y -> regA | weight converts
  cvt_pool<<<7104, 256, 0, stream>>>(y, regA, Wq, Wkv, Wproj, Wsr,
                                     Wq_b, Wkv_b, Wproj_b, Wsr_b);

  // co-dispatched: q-proj GEMM (196 blocks) + sr conv+LN+GELU (196 blocks)
  qsr_gemm<<<392, 512, 0, stream>>>(x, Wq_b, q_win,
                                    regA, Wsr_b, bsr, gn, bn, regC);

  // mega-fused kv-proj + attention + out-proj -> f32 d_out
  kvattn<<<512, 1024, 0, stream>>>(regC, Wkv_b, q_win, Wproj_b, bproj, out);
}

// Round 18
// 135.726 us; speedup vs baseline: 1.0215x; 1.0176x over previous
//
#include <hip/hip_runtime.h>
#include <hip/hip_bf16.h>

// ---------- common ----------
typedef __attribute__((ext_vector_type(8))) short short8;
typedef __attribute__((ext_vector_type(4))) float f32x4;
typedef __attribute__((ext_vector_type(4))) unsigned short ushort4v;

#define DI __device__ __forceinline__

DI unsigned short f2bf(float f) {
  union { float f; unsigned int u; } a; a.f = f;
  unsigned int u = a.u;
  return (unsigned short)((u + 0x7FFFu + ((u >> 16) & 1u)) >> 16);
}

#define BARRIER() do { asm volatile("" ::: "memory"); __builtin_amdgcn_s_barrier(); asm volatile("" ::: "memory"); } while (0)
#define GLOAD16(src, dst) __builtin_amdgcn_global_load_lds( \
    (const __attribute__((address_space(1))) void*)(src), \
    (__attribute__((address_space(3))) void*)(dst), 16, 0, 0)

// Problem: B=8, H1=W1=56, N1=3136, C1=512, C2=256, NH=8, HD=64, WS=7, M=25088

// ---------- merged: 2x2 avgpool(+cvt) for y | weight f32->bf16 converts ----------
__global__ __launch_bounds__(256)
void cvt_pool(const float* __restrict__ y, unsigned short* __restrict__ pooled,
              const float* __restrict__ Wq, const float* __restrict__ Wkv,
              const float* __restrict__ Wproj, const float* __restrict__ Wsr,
              unsigned short* __restrict__ Wq_b, unsigned short* __restrict__ Wkv_b,
              unsigned short* __restrict__ Wproj_b, unsigned short* __restrict__ Wsr_b) {
  int bid = blockIdx.x;
  if (bid < 6272) {
    int t = bid * 256 + threadIdx.x;
    int cv = (t & 63) * 4;
    int bp = t >> 6;
    int b = bp / 3136, p = bp % 3136;
    int hp = p / 56, wp = p % 56;
    const float* src = y + (((size_t)b * 12544) + hp * 224 + wp * 2) * 256 + cv;
    float4 a0 = *(const float4*)(src);
    float4 a1 = *(const float4*)(src + 256);
    float4 a2 = *(const float4*)(src + 28672);
    float4 a3 = *(const float4*)(src + 28672 + 256);
    float4 av;
    av.x = (a0.x + a1.x + a2.x + a3.x) * 0.25f;
    av.y = (a0.y + a1.y + a2.y + a3.y) * 0.25f;
    av.z = (a0.z + a1.z + a2.z + a3.z) * 0.25f;
    av.w = (a0.w + a1.w + a2.w + a3.w) * 0.25f;
    ushort4v o = { f2bf(av.x), f2bf(av.y), f2bf(av.z), f2bf(av.w) };
    *(ushort4v*)&pooled[(size_t)bp * 256 + cv] = o;
  } else {
    long i = (long)(bid - 6272) * 1024 + threadIdx.x * 4;
    const float* src; unsigned short* dst; long off;
    if (i < 262144L)      { src = Wq;    dst = Wq_b;    off = i; }
    else if (i < 524288L) { src = Wkv;   dst = Wkv_b;   off = i - 262144L; }
    else if (i < 786432L) { src = Wproj; dst = Wproj_b; off = i - 524288L; }
    else                  { src = Wsr;   dst = Wsr_b;   off = i - 786432L; }
    float4 v = *(const float4*)&src[off];
    ushort4v o = { f2bf(v.x), f2bf(v.y), f2bf(v.z), f2bf(v.w) };
    *(ushort4v*)&dst[off] = o;
  }
}

// ---------- q-window scatter epilogue ----------
DI void epi_q(int gm, int gc, float v, unsigned short* outp) {
  const int b = gm / 3136, pos = gm % 3136;
  const int h = pos / 56, ww = pos % 56;
  const int head = gc >> 6, d = gc & 63;
  const size_t idx = ((((size_t)(b * 8 + head)) * 64 + (h / 7) * 8 + (ww / 7)) * 49
                      + (h % 7) * 7 + (ww % 7)) * 64 + d;
  outp[idx] = f2bf(v);
}

// ---------- merged dispatch: q-proj GEMM (blocks 0..195) | sr conv+LN+GELU (196..391) ----------
__global__ __launch_bounds__(512, 2)
void qsr_gemm(const float* __restrict__ A,
              const unsigned short* __restrict__ Bw,
              unsigned short* __restrict__ outp,
              const unsigned short* __restrict__ Ap,
              const unsigned short* __restrict__ Wsr_b,
              const float* __restrict__ bsr, const float* __restrict__ gn,
              const float* __restrict__ bn, unsigned short* __restrict__ y2out) {
  __shared__ unsigned short lds[65536];
  const int bid = blockIdx.x;
  const int tid = threadIdx.x;
  const int wv = tid >> 6;
  const int lane = tid & 63;
  const int lr = lane & 15;
  const int lg = lane >> 4;
  const int lr4 = lg * 4;
  const int srow8 = lane >> 3;
  const int sl8 = lane & 7;

  if (bid < 196) {
    const int wm = wv >> 2;
    const int wn = wv & 3;
    const int m0 = (bid >> 1) * 256;
    const int n0 = (bid & 1) * 256;
    constexpr int K = 512, NT = K / 64;

    f32x4 acc[8][4];
#pragma unroll
    for (int i = 0; i < 8; ++i)
#pragma unroll
      for (int j = 0; j < 4; ++j) acc[i][j] = (f32x4){0.f, 0.f, 0.f, 0.f};

    float4 fa[4][2];
    auto loadA = [&](int t1) {
      int tsrc = (t1 < NT) ? t1 : NT - 1;
#pragma unroll
      for (int rr = 0; rr < 4; ++rr) {
        int trow = rr * 64 + wv * 8 + srow8;
        const float* p = A + (size_t)(m0 + trow) * K + tsrc * 64 + sl8 * 8;
        fa[rr][0] = *(const float4*)p;
        fa[rr][1] = *(const float4*)(p + 4);
      }
      asm volatile("" ::: "memory");
    };
    auto writeA = [&](int t1) {
#pragma unroll
      for (int rr = 0; rr < 4; ++rr) {
        int trow = rr * 64 + wv * 8 + srow8;
        union { short8 s; unsigned short u[8]; } w;
        w.u[0] = f2bf(fa[rr][0].x); w.u[1] = f2bf(fa[rr][0].y);
        w.u[2] = f2bf(fa[rr][0].z); w.u[3] = f2bf(fa[rr][0].w);
        w.u[4] = f2bf(fa[rr][1].x); w.u[5] = f2bf(fa[rr][1].y);
        w.u[6] = f2bf(fa[rr][1].z); w.u[7] = f2bf(fa[rr][1].w);
        *(short8*)&lds[(t1 & 1) * 32768 + trow * 64 + ((sl8 ^ (trow & 7)) * 8)] = w.s;
      }
    };
    auto stageB = [&](int t1, int rr) {
      int tsrc = (t1 < NT) ? t1 : NT - 1;
      int trow = rr * 64 + wv * 8 + srow8;
      int sx = sl8 ^ (trow & 7);
      GLOAD16(Bw + (size_t)(n0 + trow) * K + tsrc * 64 + sx * 8,
              &lds[(t1 & 1) * 32768 + 16384 + (rr * 64 + wv * 8) * 64]);
    };
    auto rdA = [&](int s, int mf, int ks) -> short8 {
      int row = wm * 128 + mf * 16 + lr;
      int slot = ((ks << 2) + lg) ^ (row & 7);
      return *(const short8*)&lds[s * 32768 + row * 64 + slot * 8];
    };
    auto rdB = [&](int s, int nf, int ks) -> short8 {
      int row = wn * 64 + nf * 16 + lr;
      int slot = ((ks << 2) + lg) ^ (row & 7);
      return *(const short8*)&lds[s * 32768 + 16384 + row * 64 + slot * 8];
    };

    stageB(0, 0); stageB(0, 1); stageB(0, 2); stageB(0, 3);
    loadA(0);
    asm volatile("s_waitcnt vmcnt(0)" ::: "memory");
    writeA(0);
    asm volatile("s_waitcnt lgkmcnt(0)" ::: "memory");
    BARRIER();

    for (int t = 0; t < NT; ++t) {
      const int s = t & 1;
      short8 bfr[4][2];
      loadA(t + 1);
#pragma unroll
      for (int j = 0; j < 4; ++j) { bfr[j][0] = rdB(s, j, 0); bfr[j][1] = rdB(s, j, 1); }
      {
        short8 x0 = rdA(s, 0, 0), x1 = rdA(s, 0, 1);
        short8 y0 = rdA(s, 1, 0), y1 = rdA(s, 1, 1);
        BARRIER();
        __builtin_amdgcn_s_setprio(1);
#pragma unroll
        for (int j = 0; j < 4; ++j) {
          acc[0][j] = __builtin_amdgcn_mfma_f32_16x16x32_bf16(x0, bfr[j][0], acc[0][j], 0, 0, 0);
          acc[0][j] = __builtin_amdgcn_mfma_f32_16x16x32_bf16(x1, bfr[j][1], acc[0][j], 0, 0, 0);
          acc[1][j] = __builtin_amdgcn_mfma_f32_16x16x32_bf16(y0, bfr[j][0], acc[1][j], 0, 0, 0);
          acc[1][j] = __builtin_amdgcn_mfma_f32_16x16x32_bf16(y1, bfr[j][1], acc[1][j], 0, 0, 0);
        }
        __builtin_amdgcn_s_setprio(0);
        BARRIER();
      }
      stageB(t + 1, 0); stageB(t + 1, 1);
      {
        short8 x0 = rdA(s, 2, 0), x1 = rdA(s, 2, 1);
        short8 y0 = rdA(s, 3, 0), y1 = rdA(s, 3, 1);
        BARRIER();
        __builtin_amdgcn_s_setprio(1);
#pragma unroll
        for (int j = 0; j < 4; ++j) {
          acc[2][j] = __builtin_amdgcn_mfma_f32_16x16x32_bf16(x0, bfr[j][0], acc[2][j], 0, 0, 0);
          acc[2][j] = __builtin_amdgcn_mfma_f32_16x16x32_bf16(x1, bfr[j][1], acc[2][j], 0, 0, 0);
          acc[3][j] = __builtin_amdgcn_mfma_f32_16x16x32_bf16(y0, bfr[j][0], acc[3][j], 0, 0, 0);
          acc[3][j] = __builtin_amdgcn_mfma_f32_16x16x32_bf16(y1, bfr[j][1], acc[3][j], 0, 0, 0);
        }
        __builtin_amdgcn_s_setprio(0);
        BARRIER();
      }
      stageB(t + 1, 2); stageB(t + 1, 3);
      {
        short8 x0 = rdA(s, 4, 0), x1 = rdA(s, 4, 1);
        short8 y0 = rdA(s, 5, 0), y1 = rdA(s, 5, 1);
        BARRIER();
        __builtin_amdgcn_s_setprio(1);
#pragma unroll
        for (int j = 0; j < 4; ++j) {
          acc[4][j] = __builtin_amdgcn_mfma_f32_16x16x32_bf16(x0, bfr[j][0], acc[4][j], 0, 0, 0);
          acc[4][j] = __builtin_amdgcn_mfma_f32_16x16x32_bf16(x1, bfr[j][1], acc[4][j], 0, 0, 0);
          acc[5][j] = __builtin_amdgcn_mfma_f32_16x16x32_bf16(y0, bfr[j][0], acc[5][j], 0, 0, 0);
          acc[5][j] = __builtin_amdgcn_mfma_f32_16x16x32_bf16(y1, bfr[j][1], acc[5][j], 0, 0, 0);
        }
        __builtin_amdgcn_s_setprio(0);
        BARRIER();
      }
      {
        short8 x0 = rdA(s, 6, 0), x1 = rdA(s, 6, 1);
        short8 y0 = rdA(s, 7, 0), y1 = rdA(s, 7, 1);
        asm volatile("s_waitcnt vmcnt(4)" ::: "memory");
        writeA(t + 1);
        asm volatile("s_waitcnt lgkmcnt(0)" ::: "memory");
        BARRIER();
        __builtin_amdgcn_s_setprio(1);
#pragma unroll
        for (int j = 0; j < 4; ++j) {
          acc[6][j] = __builtin_amdgcn_mfma_f32_16x16x32_bf16(x0, bfr[j][0], acc[6][j], 0, 0, 0);
          acc[6][j] = __builtin_amdgcn_mfma_f32_16x16x32_bf16(x1, bfr[j][1], acc[6][j], 0, 0, 0);
          acc[7][j] = __builtin_amdgcn_mfma_f32_16x16x32_bf16(y0, bfr[j][0], acc[7][j], 0, 0, 0);
          acc[7][j] = __builtin_amdgcn_mfma_f32_16x16x32_bf16(y1, bfr[j][1], acc[7][j], 0, 0, 0);
        }
        __builtin_amdgcn_s_setprio(0);
        asm volatile("s_waitcnt vmcnt(0)" ::: "memory");
        BARRIER();
      }
    }

#pragma unroll
    for (int i = 0; i < 8; ++i)
#pragma unroll
      for (int j = 0; j < 4; ++j)
#pragma unroll
        for (int r = 0; r < 4; ++r)
          epi_q(m0 + wm * 128 + i * 16 + lr4 + r, n0 + wn * 64 + j * 16 + lr,
                acc[i][j][r], outp);
  } else {
    // ---- sr: conv GEMM + bias + LN + GELU, 128 rows/block, shared Wsr B-tile ----
    unsigned short* sA = lds;
    unsigned short* sB = lds + 8192;
    float* red = (float*)&lds[24576];
    const int tl = wv >> 2;
    const int w4 = wv & 3;
    const int m0 = (bid - 196) * 128;

    f32x4 acc[4][4];
#pragma unroll
    for (int i = 0; i < 4; ++i)
#pragma unroll
      for (int j = 0; j < 4; ++j) acc[i][j] = (f32x4){0.f, 0.f, 0.f, 0.f};

    for (int kt = 0; kt < 256; kt += 64) {
#pragma unroll
      for (int c = 0; c < 2; ++c) {
        int row = tl * 64 + w4 * 16 + c * 8 + srow8;
        GLOAD16(Ap + (size_t)(m0 + row) * 256 + kt + ((sl8 ^ srow8) * 8),
                &sA[row * 64]);
      }
#pragma unroll
      for (int c = 0; c < 4; ++c) {
        int row = wv * 32 + c * 8 + srow8;
        GLOAD16(Wsr_b + (size_t)row * 256 + kt + ((sl8 ^ srow8) * 8),
                &sB[row * 64]);
      }
      __syncthreads();
#pragma unroll
      for (int ks = 0; ks < 2; ++ks) {
        short8 af[4], bfr[4];
#pragma unroll
        for (int i = 0; i < 4; ++i)
          af[i] = *(const short8*)&sA[(tl * 64 + i * 16 + lr) * 64 + (((ks * 4 + lg) ^ (lr & 7)) * 8)];
#pragma unroll
        for (int j = 0; j < 4; ++j)
          bfr[j] = *(const short8*)&sB[(w4 * 64 + j * 16 + lr) * 64 + (((ks * 4 + lg) ^ (lr & 7)) * 8)];
#pragma unroll
        for (int i = 0; i < 4; ++i)
#pragma unroll
          for (int j = 0; j < 4; ++j)
            acc[i][j] = __builtin_amdgcn_mfma_f32_16x16x32_bf16(af[i], bfr[j], acc[i][j], 0, 0, 0);
      }
      __syncthreads();
    }

    float bsv[4], gnv[4], bnv[4];
#pragma unroll
    for (int j = 0; j < 4; ++j) {
      int col = w4 * 64 + j * 16 + lr;
      bsv[j] = bsr[col]; gnv[j] = gn[col]; bnv[j] = bn[col];
    }
    float s_[4][4], q_[4][4];
#pragma unroll
    for (int i = 0; i < 4; ++i)
#pragma unroll
      for (int r = 0; r < 4; ++r) {
        float s = 0.f, q = 0.f;
#pragma unroll
        for (int j = 0; j < 4; ++j) {
          float v = acc[i][j][r] + bsv[j];
          acc[i][j][r] = v;
          s += v; q += v * v;
        }
        s_[i][r] = s; q_[i][r] = q;
      }
#pragma unroll
    for (int m = 1; m <= 8; m <<= 1)
#pragma unroll
      for (int i = 0; i < 4; ++i)
#pragma unroll
        for (int r = 0; r < 4; ++r) {
          s_[i][r] += __shfl_xor(s_[i][r], m);
          q_[i][r] += __shfl_xor(q_[i][r], m);
        }
    if (lr == 0) {
#pragma unroll
      for (int i = 0; i < 4; ++i)
#pragma unroll
        for (int r = 0; r < 4; ++r) {
          int row = i * 16 + lr4 + r;
          red[(tl * 64 + row) * 8 + w4 * 2 + 0] = s_[i][r];
          red[(tl * 64 + row) * 8 + w4 * 2 + 1] = q_[i][r];
        }
    }
    __syncthreads();
#pragma unroll
    for (int i = 0; i < 4; ++i) {
#pragma unroll
      for (int r = 0; r < 4; ++r) {
        int row = i * 16 + lr4 + r;
        const float* rd = &red[(tl * 64 + row) * 8];
        float sum = rd[0] + rd[2] + rd[4] + rd[6];
        float sq  = rd[1] + rd[3] + rd[5] + rd[7];
        float mean = sum * (1.f / 256.f);
        float var = sq * (1.f / 256.f) - mean * mean;
        float rstd = rsqrtf(var + 1e-5f);
#pragma unroll
        for (int j = 0; j < 4; ++j) {
          float t = (acc[i][j][r] - mean) * rstd * gnv[j] + bnv[j];
          t = 0.5f * t * (1.f + erff(t * 0.70710678118654752f));
          y2out[(size_t)(m0 + tl * 64 + row) * 256 + w4 * 64 + j * 16 + lr] = f2bf(t);
        }
      }
    }
  }
}

// ---------- mega-fused kv-proj + attention + out-proj: 16 waves = 8 heads x 2 halves ----------
// R8 structure (h2-major Wkv staging — do not reorder; kt-major thrashes L2, +46MB FETCH).
// V^T writes packed to b64. T5: setprio(1) around MFMA clusters (barrier-free kv loop has
// genuine wave role-diversity -> scheduler can favor MFMA-ready waves over staging waves).
__global__ __launch_bounds__(1024)
void kvattn(const unsigned short* __restrict__ y2,
            const unsigned short* __restrict__ Wkv_b,
            const unsigned short* __restrict__ qwin,
            const unsigned short* __restrict__ Wproj_b,
            const float* __restrict__ bproj,
            float* __restrict__ out) {
  __shared__ unsigned short lds[81920];
  const int tid = threadIdx.x;
  const int wv16 = tid >> 6;
  const int head = wv16 >> 1;
  const int half = wv16 & 1;
  const int lane = tid & 63;
  const int lr = lane & 15;
  const int lg = lane >> 4;
  const int r8 = lane >> 3;
  const int sl8 = lane & 7;
  const int bb = blockIdx.x >> 6;
  const int win = blockIdx.x & 63;
  const int ht = win >> 3, wt = win & 7;

  unsigned short* Cy  = lds;
  unsigned short* SLh = lds + 16384 + head * 8192;
  unsigned short* OA  = lds + 16384;
  unsigned short* WPs = lds + 49152 + wv16 * 2048;

  {
    int rb = wv16 & 7;
    int m = rb * 8 + r8;
    int mm = (m < 49) ? m : 48;
    int grow = bb * 3136 + (ht * 7 + mm / 7) * 56 + wt * 7 + (mm % 7);
    int p0 = wv16 >> 3;
#pragma unroll
    for (int pp = 0; pp < 2; ++pp) {
      int panel = p0 + pp * 2;
      GLOAD16(y2 + (size_t)grow * 256 + panel * 64 + ((sl8 ^ (m & 7)) * 8),
              &Cy[panel * 4096 + rb * 512]);
    }
  }

  auto stageW = [&](int s) {  // h2-major: h2 = s>>2, kt = s&3
    int h2 = s >> 2, kt = s & 3;
#pragma unroll
    for (int c = 0; c < 4; ++c) {
      int lrow = half * 32 + c * 8 + r8;
      GLOAD16(Wkv_b + (size_t)(h2 * 512 + head * 64 + lrow) * 256 + kt * 64 + ((sl8 ^ r8) * 8),
              &SLh[(s & 1) * 4096 + (half * 32 + c * 8) * 64]);
    }
  };

  f32x4 aK[4][2], aV[4][2];
#pragma unroll
  for (int i = 0; i < 4; ++i)
#pragma unroll
    for (int j = 0; j < 2; ++j) { aK[i][j] = (f32x4){0,0,0,0}; aV[i][j] = (f32x4){0,0,0,0}; }

  stageW(0);
  asm volatile("s_waitcnt vmcnt(4)" ::: "memory");
  BARRIER();  // (1) Cy visible

#pragma unroll
  for (int s = 0; s < 8; ++s) {
    if (s < 7) {
      stageW(s + 1);
      asm volatile("s_waitcnt vmcnt(4)" ::: "memory");
    } else {
      asm volatile("s_waitcnt vmcnt(0)" ::: "memory");
    }
    const int kt = s & 3;
    const unsigned short* Wb = &SLh[(s & 1) * 4096];
    short8 bfrg[2][2];
#pragma unroll
    for (int nf2 = 0; nf2 < 2; ++nf2)
#pragma unroll
      for (int ks = 0; ks < 2; ++ks) {
        int row = (half * 2 + nf2) * 16 + lr;
        bfrg[nf2][ks] = *(const short8*)&Wb[row * 64 + (((ks * 4 + lg) ^ (lr & 7)) * 8)];
      }
    __builtin_amdgcn_s_setprio(1);
#pragma unroll
    for (int mf = 0; mf < 4; ++mf)
#pragma unroll
      for (int ks = 0; ks < 2; ++ks) {
        short8 af = *(const short8*)&Cy[kt * 4096 + (mf * 16 + lr) * 64 + (((ks * 4 + lg) ^ (lr & 7)) * 8)];
#pragma unroll
        for (int nf2 = 0; nf2 < 2; ++nf2) {
          if (s < 4)
            aK[mf][nf2] = __builtin_amdgcn_mfma_f32_16x16x32_bf16(af, bfrg[nf2][ks], aK[mf][nf2], 0, 0, 0);
          else
            aV[mf][nf2] = __builtin_amdgcn_mfma_f32_16x16x32_bf16(af, bfrg[nf2][ks], aV[mf][nf2], 0, 0, 0);
        }
      }
    __builtin_amdgcn_s_setprio(0);
  }

  const unsigned short* qb = qwin + (size_t)((bb * 8 + head) * 64 + win) * 3136;
  short8 qf[2][2];
#pragma unroll
  for (int mf2 = 0; mf2 < 2; ++mf2)
#pragma unroll
    for (int ks = 0; ks < 2; ++ks)
      qf[mf2][ks] = *(const short8*)&qb[((half * 2 + mf2) * 16 + lr) * 64 + ks * 32 + lg * 8];

  BARRIER();  // (2) staged Wkv fully consumed -> overwrite with K/V

#pragma unroll
  for (int mf = 0; mf < 4; ++mf)
#pragma unroll
    for (int nf2 = 0; nf2 < 2; ++nf2) {
      int d = (half * 2 + nf2) * 16 + lr;
#pragma unroll
      for (int r = 0; r < 4; ++r) {
        int key = mf * 16 + lg * 4 + r;
        SLh[key * 64 + (((d >> 3) ^ (key & 7)) * 8) + (d & 7)] = f2bf(aK[mf][nf2][r]);
      }
      int slotv = (mf * 2 + (lg >> 1)) ^ (d & 7);
      ushort4v pv = { f2bf(aV[mf][nf2][0]), f2bf(aV[mf][nf2][1]),
                      f2bf(aV[mf][nf2][2]), f2bf(aV[mf][nf2][3]) };
      *(ushort4v*)&SLh[4096 + d * 64 + slotv * 8 + (lg & 1) * 4] = pv;
    }
  asm volatile("s_waitcnt lgkmcnt(0)" ::: "memory");
  BARRIER();  // (3) K & V^T complete

  f32x4 aS[2][4];
#pragma unroll
  for (int i = 0; i < 2; ++i)
#pragma unroll
    for (int j = 0; j < 4; ++j) aS[i][j] = (f32x4){0,0,0,0};
  __builtin_amdgcn_s_setprio(1);
#pragma unroll
  for (int mf2 = 0; mf2 < 2; ++mf2)
#pragma unroll
    for (int ks = 0; ks < 2; ++ks)
#pragma unroll
      for (int nf = 0; nf < 4; ++nf) {
        short8 bk = *(const short8*)&SLh[(nf * 16 + lr) * 64 + (((ks * 4 + lg) ^ (lr & 7)) * 8)];
        aS[mf2][nf] = __builtin_amdgcn_mfma_f32_16x16x32_bf16(qf[mf2][ks], bk, aS[mf2][nf], 0, 0, 0);
      }
  __builtin_amdgcn_s_setprio(0);

#pragma unroll
  for (int nf = 0; nf < 4; ++nf)
    if (nf * 16 + lr >= 49) {
#pragma unroll
      for (int mf2 = 0; mf2 < 2; ++mf2)
#pragma unroll
        for (int r = 0; r < 4; ++r) aS[mf2][nf][r] = -1e30f;
    }
  const float cexp = 0.125f * 1.4426950408889634f;
  float mx[2][4], sm[2][4];
#pragma unroll
  for (int mf2 = 0; mf2 < 2; ++mf2)
#pragma unroll
    for (int r = 0; r < 4; ++r)
      mx[mf2][r] = fmaxf(fmaxf(aS[mf2][0][r], aS[mf2][1][r]), fmaxf(aS[mf2][2][r], aS[mf2][3][r]));
#pragma unroll
  for (int m = 1; m <= 8; m <<= 1)
#pragma unroll
    for (int mf2 = 0; mf2 < 2; ++mf2)
#pragma unroll
      for (int r = 0; r < 4; ++r) mx[mf2][r] = fmaxf(mx[mf2][r], __shfl_xor(mx[mf2][r], m));
#pragma unroll
  for (int mf2 = 0; mf2 < 2; ++mf2)
#pragma unroll
    for (int nf = 0; nf < 4; ++nf)
#pragma unroll
      for (int r = 0; r < 4; ++r)
        aS[mf2][nf][r] = exp2f((aS[mf2][nf][r] - mx[mf2][r]) * cexp);
#pragma unroll
  for (int mf2 = 0; mf2 < 2; ++mf2)
#pragma unroll
    for (int r = 0; r < 4; ++r)
      sm[mf2][r] = aS[mf2][0][r] + aS[mf2][1][r] + aS[mf2][2][r] + aS[mf2][3][r];
#pragma unroll
  for (int m = 1; m <= 8; m <<= 1)
#pragma unroll
    for (int mf2 = 0; mf2 < 2; ++mf2)
#pragma unroll
      for (int r = 0; r < 4; ++r) sm[mf2][r] += __shfl_xor(sm[mf2][r], m);
#pragma unroll
  for (int mf2 = 0; mf2 < 2; ++mf2)
#pragma unroll
    for (int r = 0; r < 4; ++r) sm[mf2][r] = 1.f / sm[mf2][r];

  BARRIER();  // (4) K reads done -> overwrite buf0 with P

#pragma unroll
  for (int mf2 = 0; mf2 < 2; ++mf2)
#pragma unroll
    for (int nf = 0; nf < 4; ++nf)
#pragma unroll
      for (int r = 0; r < 4; ++r) {
        int q = (half * 2 + mf2) * 16 + lg * 4 + r;
        int key = nf * 16 + lr;
        SLh[q * 64 + (((key >> 3) ^ (q & 7)) * 8) + (key & 7)] = f2bf(aS[mf2][nf][r] * sm[mf2][r]);
      }

  f32x4 aO[2][4];
#pragma unroll
  for (int i = 0; i < 2; ++i)
#pragma unroll
    for (int j = 0; j < 4; ++j) aO[i][j] = (f32x4){0,0,0,0};
  __builtin_amdgcn_s_setprio(1);
#pragma unroll
  for (int mf2 = 0; mf2 < 2; ++mf2)
#pragma unroll
    for (int ks = 0; ks < 2; ++ks) {
      int qrow = (half * 2 + mf2) * 16 + lr;
      short8 pf = *(const short8*)&SLh[qrow * 64 + (((ks * 4 + lg) ^ (lr & 7)) * 8)];
#pragma unroll
      for (int df = 0; df < 4; ++df) {
        short8 vf = *(const short8*)&SLh[4096 + (df * 16 + lr) * 64 + (((ks * 4 + lg) ^ (lr & 7)) * 8)];
        aO[mf2][df] = __builtin_amdgcn_mfma_f32_16x16x32_bf16(pf, vf, aO[mf2][df], 0, 0, 0);
      }
    }
  __builtin_amdgcn_s_setprio(0);

  BARRIER();  // (5) PV done -> SL regions reusable as OA / WP

#pragma unroll
  for (int mf2 = 0; mf2 < 2; ++mf2)
#pragma unroll
    for (int df = 0; df < 4; ++df)
#pragma unroll
      for (int r = 0; r < 4; ++r) {
        int q = (half * 2 + mf2) * 16 + lg * 4 + r;
        int slot = df * 2 + (lr >> 3);
        OA[q * 512 + head * 64 + ((slot ^ (q & 7)) * 8) + (lr & 7)] = f2bf(aO[mf2][df][r]);
      }
#pragma unroll
  for (int c = 0; c < 4; ++c) {
    int lrow = c * 8 + r8;
    GLOAD16(Wproj_b + (size_t)(head * 64 + half * 32 + lrow) * 512 + ((sl8 ^ r8) * 8),
            &WPs[c * 512]);
  }
  asm volatile("s_waitcnt lgkmcnt(0) vmcnt(0)" ::: "memory");
  BARRIER();  // (6) OA + WP(0) ready

  f32x4 aR[4][2];
#pragma unroll
  for (int i = 0; i < 4; ++i)
#pragma unroll
    for (int j = 0; j < 2; ++j) aR[i][j] = (f32x4){0,0,0,0};
#pragma unroll
  for (int kt = 0; kt < 8; ++kt) {
    short8 nx[4];
    if (kt < 7) {
#pragma unroll
      for (int c = 0; c < 4; ++c) {
        int lrow = c * 8 + r8;
        nx[c] = *(const short8*)&Wproj_b[(size_t)(head * 64 + half * 32 + lrow) * 512
                                         + (kt + 1) * 64 + ((sl8 ^ r8) * 8)];
      }
    }
    __builtin_amdgcn_s_setprio(1);
#pragma unroll
    for (int mf = 0; mf < 4; ++mf)
#pragma unroll
      for (int ks = 0; ks < 2; ++ks) {
        short8 af2 = *(const short8*)&OA[(mf * 16 + lr) * 512 + kt * 64 + (((ks * 4 + lg) ^ (lr & 7)) * 8)];
#pragma unroll
        for (int nf2 = 0; nf2 < 2; ++nf2) {
          short8 bf2 = *(const short8*)&WPs[(nf2 * 16 + lr) * 64 + (((ks * 4 + lg) ^ (lr & 7)) * 8)];
          aR[mf][nf2] = __builtin_amdgcn_mfma_f32_16x16x32_bf16(af2, bf2, aR[mf][nf2], 0, 0, 0);
        }
      }
    __builtin_amdgcn_s_setprio(0);
    if (kt < 7) {
#pragma unroll
      for (int c = 0; c < 4; ++c)
        *(short8*)&WPs[(c * 8 + r8) * 64 + sl8 * 8] = nx[c];
    }
  }

#pragma unroll
  for (int mf = 0; mf < 4; ++mf)
#pragma unroll
    for (int nf2 = 0; nf2 < 2; ++nf2)
#pragma unroll
      for (int r = 0; r < 4; ++r) {
        int q = mf * 16 + lg * 4 + r;
        if (q < 49) {
          int gm = bb * 3136 + (ht * 7 + q / 7) * 56 + wt * 7 + (q % 7);
          int col = head * 64 + (half * 2 + nf2) * 16 + lr;
          out[(size_t)gm * 512 + col] = aR[mf][nf2][r] + bproj[col];
        }
      }
}

// ---------- launcher ----------
extern "C" void kernel_launch(void* const* d_in, const int* in_sizes, int n_in,
                              void* d_out, int out_size, void* d_ws, size_t ws_size,
                              hipStream_t stream) {
  const float* x     = (const float*)d_in[0];
  const float* y     = (const float*)d_in[1];
  const float* Wq    = (const float*)d_in[2];
  const float* Wkv   = (const float*)d_in[3];
  const float* Wproj = (const float*)d_in[4];
  const float* bproj = (const float*)d_in[5];
  const float* Wsr   = (const float*)d_in[6];
  const float* bsr   = (const float*)d_in[7];
  const float* gn    = (const float*)d_in[8];
  const float* bn    = (const float*)d_in[9];
  float* out = (float*)d_out;

  char* ws = (char*)d_ws;
  unsigned short* Wq_b    = (unsigned short*)ws; ws += 524288;
  unsigned short* Wkv_b   = (unsigned short*)ws; ws += 524288;
  unsigned short* Wproj_b = (unsigned short*)ws; ws += 524288;
  unsigned short* Wsr_b   = (unsigned short*)ws; ws += 131072;
  unsigned short* regA    = (unsigned short*)ws; ws += 12845056; // pooled bf16
  unsigned short* q_win   = (unsigned short*)ws; ws += 25690112; // q windows
  unsigned short* regC    = (unsigned short*)ws; ws += 12845056; // y2 bf16

  // pool y -> regA | weight converts
  cvt_pool<<<7104, 256, 0, stream>>>(y, regA, Wq, Wkv, Wproj, Wsr,
                                     Wq_b, Wkv_b, Wproj_b, Wsr_b);

  // co-dispatched: q-proj GEMM (196 blocks) + sr conv+LN+GELU (196 blocks)
  qsr_gemm<<<392, 512, 0, stream>>>(x, Wq_b, q_win,
                                    regA, Wsr_b, bsr, gn, bn, regC);

  // mega-fused kv-proj + attention + out-proj (T5 setprio) -> f32 d_out
  kvattn<<<512, 1024, 0, stream>>>(regC, Wkv_b, q_win, Wproj_b, bproj, out);
}

// Round 19
// 135.666 us; speedup vs baseline: 1.0219x; 1.0004x over previous
//
#include <hip/hip_runtime.h>
#include <hip/hip_bf16.h>

// ---------- common ----------
typedef __attribute__((ext_vector_type(8))) short short8;
typedef __attribute__((ext_vector_type(4))) float f32x4;
typedef __attribute__((ext_vector_type(4))) unsigned short ushort4v;

#define DI __device__ __forceinline__

DI unsigned short f2bf(float f) {
  union { float f; unsigned int u; } a; a.f = f;
  unsigned int u = a.u;
  return (unsigned short)((u + 0x7FFFu + ((u >> 16) & 1u)) >> 16);
}

#define BARRIER() do { asm volatile("" ::: "memory"); __builtin_amdgcn_s_barrier(); asm volatile("" ::: "memory"); } while (0)
#define GLOAD16(src, dst) __builtin_amdgcn_global_load_lds( \
    (const __attribute__((address_space(1))) void*)(src), \
    (__attribute__((address_space(3))) void*)(dst), 16, 0, 0)

// Problem: B=8, H1=W1=56, N1=3136, C1=512, C2=256, NH=8, HD=64, WS=7, M=25088

// ---------- merged: 2x2 avgpool(+cvt) for y | weight f32->bf16 converts ----------
__global__ __launch_bounds__(256)
void cvt_pool(const float* __restrict__ y, unsigned short* __restrict__ pooled,
              const float* __restrict__ Wq, const float* __restrict__ Wkv,
              const float* __restrict__ Wproj, const float* __restrict__ Wsr,
              unsigned short* __restrict__ Wq_b, unsigned short* __restrict__ Wkv_b,
              unsigned short* __restrict__ Wproj_b, unsigned short* __restrict__ Wsr_b) {
  int bid = blockIdx.x;
  if (bid < 6272) {
    int t = bid * 256 + threadIdx.x;
    int cv = (t & 63) * 4;
    int bp = t >> 6;
    int b = bp / 3136, p = bp % 3136;
    int hp = p / 56, wp = p % 56;
    const float* src = y + (((size_t)b * 12544) + hp * 224 + wp * 2) * 256 + cv;
    float4 a0 = *(const float4*)(src);
    float4 a1 = *(const float4*)(src + 256);
    float4 a2 = *(const float4*)(src + 28672);
    float4 a3 = *(const float4*)(src + 28672 + 256);
    float4 av;
    av.x = (a0.x + a1.x + a2.x + a3.x) * 0.25f;
    av.y = (a0.y + a1.y + a2.y + a3.y) * 0.25f;
    av.z = (a0.z + a1.z + a2.z + a3.z) * 0.25f;
    av.w = (a0.w + a1.w + a2.w + a3.w) * 0.25f;
    ushort4v o = { f2bf(av.x), f2bf(av.y), f2bf(av.z), f2bf(av.w) };
    *(ushort4v*)&pooled[(size_t)bp * 256 + cv] = o;
  } else {
    long i = (long)(bid - 6272) * 1024 + threadIdx.x * 4;
    const float* src; unsigned short* dst; long off;
    if (i < 262144L)      { src = Wq;    dst = Wq_b;    off = i; }
    else if (i < 524288L) { src = Wkv;   dst = Wkv_b;   off = i - 262144L; }
    else if (i < 786432L) { src = Wproj; dst = Wproj_b; off = i - 524288L; }
    else                  { src = Wsr;   dst = Wsr_b;   off = i - 786432L; }
    float4 v = *(const float4*)&src[off];
    ushort4v o = { f2bf(v.x), f2bf(v.y), f2bf(v.z), f2bf(v.w) };
    *(ushort4v*)&dst[off] = o;
  }
}

// ---------- q-window scatter epilogue ----------
DI void epi_q(int gm, int gc, float v, unsigned short* outp) {
  const int b = gm / 3136, pos = gm % 3136;
  const int h = pos / 56, ww = pos % 56;
  const int head = gc >> 6, d = gc & 63;
  const size_t idx = ((((size_t)(b * 8 + head)) * 64 + (h / 7) * 8 + (ww / 7)) * 49
                      + (h % 7) * 7 + (ww % 7)) * 64 + d;
  outp[idx] = f2bf(v);
}

// ---------- merged dispatch: q-proj GEMM (blocks 0..195) | sr conv+LN+GELU (196..391) ----------
__global__ __launch_bounds__(512, 2)
void qsr_gemm(const float* __restrict__ A,
              const unsigned short* __restrict__ Bw,
              unsigned short* __restrict__ outp,
              const unsigned short* __restrict__ Ap,
              const unsigned short* __restrict__ Wsr_b,
              const float* __restrict__ bsr, const float* __restrict__ gn,
              const float* __restrict__ bn, unsigned short* __restrict__ y2out) {
  __shared__ unsigned short lds[65536];
  const int bid = blockIdx.x;
  const int tid = threadIdx.x;
  const int wv = tid >> 6;
  const int lane = tid & 63;
  const int lr = lane & 15;
  const int lg = lane >> 4;
  const int lr4 = lg * 4;
  const int srow8 = lane >> 3;
  const int sl8 = lane & 7;

  if (bid < 196) {
    const int wm = wv >> 2;
    const int wn = wv & 3;
    const int m0 = (bid >> 1) * 256;
    const int n0 = (bid & 1) * 256;
    constexpr int K = 512, NT = K / 64;

    f32x4 acc[8][4];
#pragma unroll
    for (int i = 0; i < 8; ++i)
#pragma unroll
      for (int j = 0; j < 4; ++j) acc[i][j] = (f32x4){0.f, 0.f, 0.f, 0.f};

    float4 fa[4][2];
    auto loadA = [&](int t1) {
      int tsrc = (t1 < NT) ? t1 : NT - 1;
#pragma unroll
      for (int rr = 0; rr < 4; ++rr) {
        int trow = rr * 64 + wv * 8 + srow8;
        const float* p = A + (size_t)(m0 + trow) * K + tsrc * 64 + sl8 * 8;
        fa[rr][0] = *(const float4*)p;
        fa[rr][1] = *(const float4*)(p + 4);
      }
      asm volatile("" ::: "memory");
    };
    auto writeA = [&](int t1) {
#pragma unroll
      for (int rr = 0; rr < 4; ++rr) {
        int trow = rr * 64 + wv * 8 + srow8;
        union { short8 s; unsigned short u[8]; } w;
        w.u[0] = f2bf(fa[rr][0].x); w.u[1] = f2bf(fa[rr][0].y);
        w.u[2] = f2bf(fa[rr][0].z); w.u[3] = f2bf(fa[rr][0].w);
        w.u[4] = f2bf(fa[rr][1].x); w.u[5] = f2bf(fa[rr][1].y);
        w.u[6] = f2bf(fa[rr][1].z); w.u[7] = f2bf(fa[rr][1].w);
        *(short8*)&lds[(t1 & 1) * 32768 + trow * 64 + ((sl8 ^ (trow & 7)) * 8)] = w.s;
      }
    };
    auto stageB = [&](int t1, int rr) {
      int tsrc = (t1 < NT) ? t1 : NT - 1;
      int trow = rr * 64 + wv * 8 + srow8;
      int sx = sl8 ^ (trow & 7);
      GLOAD16(Bw + (size_t)(n0 + trow) * K + tsrc * 64 + sx * 8,
              &lds[(t1 & 1) * 32768 + 16384 + (rr * 64 + wv * 8) * 64]);
    };
    auto rdA = [&](int s, int mf, int ks) -> short8 {
      int row = wm * 128 + mf * 16 + lr;
      int slot = ((ks << 2) + lg) ^ (row & 7);
      return *(const short8*)&lds[s * 32768 + row * 64 + slot * 8];
    };
    auto rdB = [&](int s, int nf, int ks) -> short8 {
      int row = wn * 64 + nf * 16 + lr;
      int slot = ((ks << 2) + lg) ^ (row & 7);
      return *(const short8*)&lds[s * 32768 + 16384 + row * 64 + slot * 8];
    };

    stageB(0, 0); stageB(0, 1); stageB(0, 2); stageB(0, 3);
    loadA(0);
    asm volatile("s_waitcnt vmcnt(0)" ::: "memory");
    writeA(0);
    asm volatile("s_waitcnt lgkmcnt(0)" ::: "memory");
    BARRIER();

    for (int t = 0; t < NT; ++t) {
      const int s = t & 1;
      short8 bfr[4][2];
      loadA(t + 1);
#pragma unroll
      for (int j = 0; j < 4; ++j) { bfr[j][0] = rdB(s, j, 0); bfr[j][1] = rdB(s, j, 1); }
      {
        short8 x0 = rdA(s, 0, 0), x1 = rdA(s, 0, 1);
        short8 y0 = rdA(s, 1, 0), y1 = rdA(s, 1, 1);
        BARRIER();
        __builtin_amdgcn_s_setprio(1);
#pragma unroll
        for (int j = 0; j < 4; ++j) {
          acc[0][j] = __builtin_amdgcn_mfma_f32_16x16x32_bf16(x0, bfr[j][0], acc[0][j], 0, 0, 0);
          acc[0][j] = __builtin_amdgcn_mfma_f32_16x16x32_bf16(x1, bfr[j][1], acc[0][j], 0, 0, 0);
          acc[1][j] = __builtin_amdgcn_mfma_f32_16x16x32_bf16(y0, bfr[j][0], acc[1][j], 0, 0, 0);
          acc[1][j] = __builtin_amdgcn_mfma_f32_16x16x32_bf16(y1, bfr[j][1], acc[1][j], 0, 0, 0);
        }
        __builtin_amdgcn_s_setprio(0);
        BARRIER();
      }
      stageB(t + 1, 0); stageB(t + 1, 1);
      {
        short8 x0 = rdA(s, 2, 0), x1 = rdA(s, 2, 1);
        short8 y0 = rdA(s, 3, 0), y1 = rdA(s, 3, 1);
        BARRIER();
        __builtin_amdgcn_s_setprio(1);
#pragma unroll
        for (int j = 0; j < 4; ++j) {
          acc[2][j] = __builtin_amdgcn_mfma_f32_16x16x32_bf16(x0, bfr[j][0], acc[2][j], 0, 0, 0);
          acc[2][j] = __builtin_amdgcn_mfma_f32_16x16x32_bf16(x1, bfr[j][1], acc[2][j], 0, 0, 0);
          acc[3][j] = __builtin_amdgcn_mfma_f32_16x16x32_bf16(y0, bfr[j][0], acc[3][j], 0, 0, 0);
          acc[3][j] = __builtin_amdgcn_mfma_f32_16x16x32_bf16(y1, bfr[j][1], acc[3][j], 0, 0, 0);
        }
        __builtin_amdgcn_s_setprio(0);
        BARRIER();
      }
      stageB(t + 1, 2); stageB(t + 1, 3);
      {
        short8 x0 = rdA(s, 4, 0), x1 = rdA(s, 4, 1);
        short8 y0 = rdA(s, 5, 0), y1 = rdA(s, 5, 1);
        BARRIER();
        __builtin_amdgcn_s_setprio(1);
#pragma unroll
        for (int j = 0; j < 4; ++j) {
          acc[4][j] = __builtin_amdgcn_mfma_f32_16x16x32_bf16(x0, bfr[j][0], acc[4][j], 0, 0, 0);
          acc[4][j] = __builtin_amdgcn_mfma_f32_16x16x32_bf16(x1, bfr[j][1], acc[4][j], 0, 0, 0);
          acc[5][j] = __builtin_amdgcn_mfma_f32_16x16x32_bf16(y0, bfr[j][0], acc[5][j], 0, 0, 0);
          acc[5][j] = __builtin_amdgcn_mfma_f32_16x16x32_bf16(y1, bfr[j][1], acc[5][j], 0, 0, 0);
        }
        __builtin_amdgcn_s_setprio(0);
        BARRIER();
      }
      {
        short8 x0 = rdA(s, 6, 0), x1 = rdA(s, 6, 1);
        short8 y0 = rdA(s, 7, 0), y1 = rdA(s, 7, 1);
        asm volatile("s_waitcnt vmcnt(4)" ::: "memory");
        writeA(t + 1);
        asm volatile("s_waitcnt lgkmcnt(0)" ::: "memory");
        BARRIER();
        __builtin_amdgcn_s_setprio(1);
#pragma unroll
        for (int j = 0; j < 4; ++j) {
          acc[6][j] = __builtin_amdgcn_mfma_f32_16x16x32_bf16(x0, bfr[j][0], acc[6][j], 0, 0, 0);
          acc[6][j] = __builtin_amdgcn_mfma_f32_16x16x32_bf16(x1, bfr[j][1], acc[6][j], 0, 0, 0);
          acc[7][j] = __builtin_amdgcn_mfma_f32_16x16x32_bf16(y0, bfr[j][0], acc[7][j], 0, 0, 0);
          acc[7][j] = __builtin_amdgcn_mfma_f32_16x16x32_bf16(y1, bfr[j][1], acc[7][j], 0, 0, 0);
        }
        __builtin_amdgcn_s_setprio(0);
        asm volatile("s_waitcnt vmcnt(0)" ::: "memory");
        BARRIER();
      }
    }

#pragma unroll
    for (int i = 0; i < 8; ++i)
#pragma unroll
      for (int j = 0; j < 4; ++j)
#pragma unroll
        for (int r = 0; r < 4; ++r)
          epi_q(m0 + wm * 128 + i * 16 + lr4 + r, n0 + wn * 64 + j * 16 + lr,
                acc[i][j][r], outp);
  } else {
    // ---- sr: conv GEMM + bias + LN + GELU, 128 rows/block, shared Wsr B-tile ----
    unsigned short* sA = lds;
    unsigned short* sB = lds + 8192;
    float* red = (float*)&lds[24576];
    const int tl = wv >> 2;
    const int w4 = wv & 3;
    const int m0 = (bid - 196) * 128;

    f32x4 acc[4][4];
#pragma unroll
    for (int i = 0; i < 4; ++i)
#pragma unroll
      for (int j = 0; j < 4; ++j) acc[i][j] = (f32x4){0.f, 0.f, 0.f, 0.f};

    for (int kt = 0; kt < 256; kt += 64) {
#pragma unroll
      for (int c = 0; c < 2; ++c) {
        int row = tl * 64 + w4 * 16 + c * 8 + srow8;
        GLOAD16(Ap + (size_t)(m0 + row) * 256 + kt + ((sl8 ^ srow8) * 8),
                &sA[row * 64]);
      }
#pragma unroll
      for (int c = 0; c < 4; ++c) {
        int row = wv * 32 + c * 8 + srow8;
        GLOAD16(Wsr_b + (size_t)row * 256 + kt + ((sl8 ^ srow8) * 8),
                &sB[row * 64]);
      }
      __syncthreads();
#pragma unroll
      for (int ks = 0; ks < 2; ++ks) {
        short8 af[4], bfr[4];
#pragma unroll
        for (int i = 0; i < 4; ++i)
          af[i] = *(const short8*)&sA[(tl * 64 + i * 16 + lr) * 64 + (((ks * 4 + lg) ^ (lr & 7)) * 8)];
#pragma unroll
        for (int j = 0; j < 4; ++j)
          bfr[j] = *(const short8*)&sB[(w4 * 64 + j * 16 + lr) * 64 + (((ks * 4 + lg) ^ (lr & 7)) * 8)];
#pragma unroll
        for (int i = 0; i < 4; ++i)
#pragma unroll
          for (int j = 0; j < 4; ++j)
            acc[i][j] = __builtin_amdgcn_mfma_f32_16x16x32_bf16(af[i], bfr[j], acc[i][j], 0, 0, 0);
      }
      __syncthreads();
    }

    float bsv[4], gnv[4], bnv[4];
#pragma unroll
    for (int j = 0; j < 4; ++j) {
      int col = w4 * 64 + j * 16 + lr;
      bsv[j] = bsr[col]; gnv[j] = gn[col]; bnv[j] = bn[col];
    }
    float s_[4][4], q_[4][4];
#pragma unroll
    for (int i = 0; i < 4; ++i)
#pragma unroll
      for (int r = 0; r < 4; ++r) {
        float s = 0.f, q = 0.f;
#pragma unroll
        for (int j = 0; j < 4; ++j) {
          float v = acc[i][j][r] + bsv[j];
          acc[i][j][r] = v;
          s += v; q += v * v;
        }
        s_[i][r] = s; q_[i][r] = q;
      }
#pragma unroll
    for (int m = 1; m <= 8; m <<= 1)
#pragma unroll
      for (int i = 0; i < 4; ++i)
#pragma unroll
        for (int r = 0; r < 4; ++r) {
          s_[i][r] += __shfl_xor(s_[i][r], m);
          q_[i][r] += __shfl_xor(q_[i][r], m);
        }
    if (lr == 0) {
#pragma unroll
      for (int i = 0; i < 4; ++i)
#pragma unroll
        for (int r = 0; r < 4; ++r) {
          int row = i * 16 + lr4 + r;
          red[(tl * 64 + row) * 8 + w4 * 2 + 0] = s_[i][r];
          red[(tl * 64 + row) * 8 + w4 * 2 + 1] = q_[i][r];
        }
    }
    __syncthreads();
#pragma unroll
    for (int i = 0; i < 4; ++i) {
#pragma unroll
      for (int r = 0; r < 4; ++r) {
        int row = i * 16 + lr4 + r;
        const float* rd = &red[(tl * 64 + row) * 8];
        float sum = rd[0] + rd[2] + rd[4] + rd[6];
        float sq  = rd[1] + rd[3] + rd[5] + rd[7];
        float mean = sum * (1.f / 256.f);
        float var = sq * (1.f / 256.f) - mean * mean;
        float rstd = rsqrtf(var + 1e-5f);
#pragma unroll
        for (int j = 0; j < 4; ++j) {
          float t = (acc[i][j][r] - mean) * rstd * gnv[j] + bnv[j];
          t = 0.5f * t * (1.f + erff(t * 0.70710678118654752f));
          y2out[(size_t)(m0 + tl * 64 + row) * 256 + w4 * 64 + j * 16 + lr] = f2bf(t);
        }
      }
    }
  }
}

// ---------- mega-fused kv-proj + attention + out-proj: 16 waves = 8 heads x 2 halves ----------
// R8 structure (h2-major Wkv staging — do not reorder; kt-major thrashes L2, +46MB FETCH).
// V^T writes packed to b64. T5 setprio around MFMA clusters (verified -2.4us).
__global__ __launch_bounds__(1024)
void kvattn(const unsigned short* __restrict__ y2,
            const unsigned short* __restrict__ Wkv_b,
            const unsigned short* __restrict__ qwin,
            const unsigned short* __restrict__ Wproj_b,
            const float* __restrict__ bproj,
            float* __restrict__ out) {
  __shared__ unsigned short lds[81920];
  const int tid = threadIdx.x;
  const int wv16 = tid >> 6;
  const int head = wv16 >> 1;
  const int half = wv16 & 1;
  const int lane = tid & 63;
  const int lr = lane & 15;
  const int lg = lane >> 4;
  const int r8 = lane >> 3;
  const int sl8 = lane & 7;
  const int bb = blockIdx.x >> 6;
  const int win = blockIdx.x & 63;
  const int ht = win >> 3, wt = win & 7;

  unsigned short* Cy  = lds;
  unsigned short* SLh = lds + 16384 + head * 8192;
  unsigned short* OA  = lds + 16384;
  unsigned short* WPs = lds + 49152 + wv16 * 2048;

  {
    int rb = wv16 & 7;
    int m = rb * 8 + r8;
    int mm = (m < 49) ? m : 48;
    int grow = bb * 3136 + (ht * 7 + mm / 7) * 56 + wt * 7 + (mm % 7);
    int p0 = wv16 >> 3;
#pragma unroll
    for (int pp = 0; pp < 2; ++pp) {
      int panel = p0 + pp * 2;
      GLOAD16(y2 + (size_t)grow * 256 + panel * 64 + ((sl8 ^ (m & 7)) * 8),
              &Cy[panel * 4096 + rb * 512]);
    }
  }

  auto stageW = [&](int s) {  // h2-major: h2 = s>>2, kt = s&3
    int h2 = s >> 2, kt = s & 3;
#pragma unroll
    for (int c = 0; c < 4; ++c) {
      int lrow = half * 32 + c * 8 + r8;
      GLOAD16(Wkv_b + (size_t)(h2 * 512 + head * 64 + lrow) * 256 + kt * 64 + ((sl8 ^ r8) * 8),
              &SLh[(s & 1) * 4096 + (half * 32 + c * 8) * 64]);
    }
  };

  f32x4 aK[4][2], aV[4][2];
#pragma unroll
  for (int i = 0; i < 4; ++i)
#pragma unroll
    for (int j = 0; j < 2; ++j) { aK[i][j] = (f32x4){0,0,0,0}; aV[i][j] = (f32x4){0,0,0,0}; }

  stageW(0);
  asm volatile("s_waitcnt vmcnt(4)" ::: "memory");
  BARRIER();  // (1) Cy visible

#pragma unroll
  for (int s = 0; s < 8; ++s) {
    if (s < 7) {
      stageW(s + 1);
      asm volatile("s_waitcnt vmcnt(4)" ::: "memory");
    } else {
      asm volatile("s_waitcnt vmcnt(0)" ::: "memory");
    }
    const int kt = s & 3;
    const unsigned short* Wb = &SLh[(s & 1) * 4096];
    short8 bfrg[2][2];
#pragma unroll
    for (int nf2 = 0; nf2 < 2; ++nf2)
#pragma unroll
      for (int ks = 0; ks < 2; ++ks) {
        int row = (half * 2 + nf2) * 16 + lr;
        bfrg[nf2][ks] = *(const short8*)&Wb[row * 64 + (((ks * 4 + lg) ^ (lr & 7)) * 8)];
      }
    __builtin_amdgcn_s_setprio(1);
#pragma unroll
    for (int mf = 0; mf < 4; ++mf)
#pragma unroll
      for (int ks = 0; ks < 2; ++ks) {
        short8 af = *(const short8*)&Cy[kt * 4096 + (mf * 16 + lr) * 64 + (((ks * 4 + lg) ^ (lr & 7)) * 8)];
#pragma unroll
        for (int nf2 = 0; nf2 < 2; ++nf2) {
          if (s < 4)
            aK[mf][nf2] = __builtin_amdgcn_mfma_f32_16x16x32_bf16(af, bfrg[nf2][ks], aK[mf][nf2], 0, 0, 0);
          else
            aV[mf][nf2] = __builtin_amdgcn_mfma_f32_16x16x32_bf16(af, bfrg[nf2][ks], aV[mf][nf2], 0, 0, 0);
        }
      }
    __builtin_amdgcn_s_setprio(0);
  }

  const unsigned short* qb = qwin + (size_t)((bb * 8 + head) * 64 + win) * 3136;
  short8 qf[2][2];
#pragma unroll
  for (int mf2 = 0; mf2 < 2; ++mf2)
#pragma unroll
    for (int ks = 0; ks < 2; ++ks)
      qf[mf2][ks] = *(const short8*)&qb[((half * 2 + mf2) * 16 + lr) * 64 + ks * 32 + lg * 8];

  BARRIER();  // (2) staged Wkv fully consumed -> overwrite with K/V

#pragma unroll
  for (int mf = 0; mf < 4; ++mf)
#pragma unroll
    for (int nf2 = 0; nf2 < 2; ++nf2) {
      int d = (half * 2 + nf2) * 16 + lr;
#pragma unroll
      for (int r = 0; r < 4; ++r) {
        int key = mf * 16 + lg * 4 + r;
        SLh[key * 64 + (((d >> 3) ^ (key & 7)) * 8) + (d & 7)] = f2bf(aK[mf][nf2][r]);
      }
      int slotv = (mf * 2 + (lg >> 1)) ^ (d & 7);
      ushort4v pv = { f2bf(aV[mf][nf2][0]), f2bf(aV[mf][nf2][1]),
                      f2bf(aV[mf][nf2][2]), f2bf(aV[mf][nf2][3]) };
      *(ushort4v*)&SLh[4096 + d * 64 + slotv * 8 + (lg & 1) * 4] = pv;
    }
  asm volatile("s_waitcnt lgkmcnt(0)" ::: "memory");
  BARRIER();  // (3) K & V^T complete

  f32x4 aS[2][4];
#pragma unroll
  for (int i = 0; i < 2; ++i)
#pragma unroll
    for (int j = 0; j < 4; ++j) aS[i][j] = (f32x4){0,0,0,0};
  __builtin_amdgcn_s_setprio(1);
#pragma unroll
  for (int mf2 = 0; mf2 < 2; ++mf2)
#pragma unroll
    for (int ks = 0; ks < 2; ++ks)
#pragma unroll
      for (int nf = 0; nf < 4; ++nf) {
        short8 bk = *(const short8*)&SLh[(nf * 16 + lr) * 64 + (((ks * 4 + lg) ^ (lr & 7)) * 8)];
        aS[mf2][nf] = __builtin_amdgcn_mfma_f32_16x16x32_bf16(qf[mf2][ks], bk, aS[mf2][nf], 0, 0, 0);
      }
  __builtin_amdgcn_s_setprio(0);

#pragma unroll
  for (int nf = 0; nf < 4; ++nf)
    if (nf * 16 + lr >= 49) {
#pragma unroll
      for (int mf2 = 0; mf2 < 2; ++mf2)
#pragma unroll
        for (int r = 0; r < 4; ++r) aS[mf2][nf][r] = -1e30f;
    }
  const float cexp = 0.125f * 1.4426950408889634f;
  float mx[2][4], sm[2][4];
#pragma unroll
  for (int mf2 = 0; mf2 < 2; ++mf2)
#pragma unroll
    for (int r = 0; r < 4; ++r)
      mx[mf2][r] = fmaxf(fmaxf(aS[mf2][0][r], aS[mf2][1][r]), fmaxf(aS[mf2][2][r], aS[mf2][3][r]));
#pragma unroll
  for (int m = 1; m <= 8; m <<= 1)
#pragma unroll
    for (int mf2 = 0; mf2 < 2; ++mf2)
#pragma unroll
      for (int r = 0; r < 4; ++r) mx[mf2][r] = fmaxf(mx[mf2][r], __shfl_xor(mx[mf2][r], m));
#pragma unroll
  for (int mf2 = 0; mf2 < 2; ++mf2)
#pragma unroll
    for (int nf = 0; nf < 4; ++nf)
#pragma unroll
      for (int r = 0; r < 4; ++r)
        aS[mf2][nf][r] = exp2f((aS[mf2][nf][r] - mx[mf2][r]) * cexp);
#pragma unroll
  for (int mf2 = 0; mf2 < 2; ++mf2)
#pragma unroll
    for (int r = 0; r < 4; ++r)
      sm[mf2][r] = aS[mf2][0][r] + aS[mf2][1][r] + aS[mf2][2][r] + aS[mf2][3][r];
#pragma unroll
  for (int m = 1; m <= 8; m <<= 1)
#pragma unroll
    for (int mf2 = 0; mf2 < 2; ++mf2)
#pragma unroll
      for (int r = 0; r < 4; ++r) sm[mf2][r] += __shfl_xor(sm[mf2][r], m);
#pragma unroll
  for (int mf2 = 0; mf2 < 2; ++mf2)
#pragma unroll
    for (int r = 0; r < 4; ++r) sm[mf2][r] = 1.f / sm[mf2][r];

  BARRIER();  // (4) K reads done -> overwrite buf0 with P

#pragma unroll
  for (int mf2 = 0; mf2 < 2; ++mf2)
#pragma unroll
    for (int nf = 0; nf < 4; ++nf)
#pragma unroll
      for (int r = 0; r < 4; ++r) {
        int q = (half * 2 + mf2) * 16 + lg * 4 + r;
        int key = nf * 16 + lr;
        SLh[q * 64 + (((key >> 3) ^ (q & 7)) * 8) + (key & 7)] = f2bf(aS[mf2][nf][r] * sm[mf2][r]);
      }

  f32x4 aO[2][4];
#pragma unroll
  for (int i = 0; i < 2; ++i)
#pragma unroll
    for (int j = 0; j < 4; ++j) aO[i][j] = (f32x4){0,0,0,0};
  __builtin_amdgcn_s_setprio(1);
#pragma unroll
  for (int mf2 = 0; mf2 < 2; ++mf2)
#pragma unroll
    for (int ks = 0; ks < 2; ++ks) {
      int qrow = (half * 2 + mf2) * 16 + lr;
      short8 pf = *(const short8*)&SLh[qrow * 64 + (((ks * 4 + lg) ^ (lr & 7)) * 8)];
#pragma unroll
      for (int df = 0; df < 4; ++df) {
        short8 vf = *(const short8*)&SLh[4096 + (df * 16 + lr) * 64 + (((ks * 4 + lg) ^ (lr & 7)) * 8)];
        aO[mf2][df] = __builtin_amdgcn_mfma_f32_16x16x32_bf16(pf, vf, aO[mf2][df], 0, 0, 0);
      }
    }
  __builtin_amdgcn_s_setprio(0);

  BARRIER();  // (5) PV done -> SL regions reusable as OA / WP

#pragma unroll
  for (int mf2 = 0; mf2 < 2; ++mf2)
#pragma unroll
    for (int df = 0; df < 4; ++df)
#pragma unroll
      for (int r = 0; r < 4; ++r) {
        int q = (half * 2 + mf2) * 16 + lg * 4 + r;
        int slot = df * 2 + (lr >> 3);
        OA[q * 512 + head * 64 + ((slot ^ (q & 7)) * 8) + (lr & 7)] = f2bf(aO[mf2][df][r]);
      }
#pragma unroll
  for (int c = 0; c < 4; ++c) {
    int lrow = c * 8 + r8;
    GLOAD16(Wproj_b + (size_t)(head * 64 + half * 32 + lrow) * 512 + ((sl8 ^ r8) * 8),
            &WPs[c * 512]);
  }
  asm volatile("s_waitcnt lgkmcnt(0) vmcnt(0)" ::: "memory");
  BARRIER();  // (6) OA + WP(0) ready

  f32x4 aR[4][2];
#pragma unroll
  for (int i = 0; i < 4; ++i)
#pragma unroll
    for (int j = 0; j < 2; ++j) aR[i][j] = (f32x4){0,0,0,0};
#pragma unroll
  for (int kt = 0; kt < 8; ++kt) {
    short8 nx[4];
    if (kt < 7) {
#pragma unroll
      for (int c = 0; c < 4; ++c) {
        int lrow = c * 8 + r8;
        nx[c] = *(const short8*)&Wproj_b[(size_t)(head * 64 + half * 32 + lrow) * 512
                                         + (kt + 1) * 64 + ((sl8 ^ r8) * 8)];
      }
    }
    __builtin_amdgcn_s_setprio(1);
#pragma unroll
    for (int mf = 0; mf < 4; ++mf)
#pragma unroll
      for (int ks = 0; ks < 2; ++ks) {
        short8 af2 = *(const short8*)&OA[(mf * 16 + lr) * 512 + kt * 64 + (((ks * 4 + lg) ^ (lr & 7)) * 8)];
#pragma unroll
        for (int nf2 = 0; nf2 < 2; ++nf2) {
          short8 bf2 = *(const short8*)&WPs[(nf2 * 16 + lr) * 64 + (((ks * 4 + lg) ^ (lr & 7)) * 8)];
          aR[mf][nf2] = __builtin_amdgcn_mfma_f32_16x16x32_bf16(af2, bf2, aR[mf][nf2], 0, 0, 0);
        }
      }
    __builtin_amdgcn_s_setprio(0);
    if (kt < 7) {
#pragma unroll
      for (int c = 0; c < 4; ++c)
        *(short8*)&WPs[(c * 8 + r8) * 64 + sl8 * 8] = nx[c];
    }
  }

#pragma unroll
  for (int mf = 0; mf < 4; ++mf)
#pragma unroll
    for (int nf2 = 0; nf2 < 2; ++nf2)
#pragma unroll
      for (int r = 0; r < 4; ++r) {
        int q = mf * 16 + lg * 4 + r;
        if (q < 49) {
          int gm = bb * 3136 + (ht * 7 + q / 7) * 56 + wt * 7 + (q % 7);
          int col = head * 64 + (half * 2 + nf2) * 16 + lr;
          out[(size_t)gm * 512 + col] = aR[mf][nf2][r] + bproj[col];
        }
      }
}

// ---------- launcher ----------
extern "C" void kernel_launch(void* const* d_in, const int* in_sizes, int n_in,
                              void* d_out, int out_size, void* d_ws, size_t ws_size,
                              hipStream_t stream) {
  const float* x     = (const float*)d_in[0];
  const float* y     = (const float*)d_in[1];
  const float* Wq    = (const float*)d_in[2];
  const float* Wkv   = (const float*)d_in[3];
  const float* Wproj = (const float*)d_in[4];
  const float* bproj = (const float*)d_in[5];
  const float* Wsr   = (const float*)d_in[6];
  const float* bsr   = (const float*)d_in[7];
  const float* gn    = (const float*)d_in[8];
  const float* bn    = (const float*)d_in[9];
  float* out = (float*)d_out;

  char* ws = (char*)d_ws;
  unsigned short* Wq_b    = (unsigned short*)ws; ws += 524288;
  unsigned short* Wkv_b   = (unsigned short*)ws; ws += 524288;
  unsigned short* Wproj_b = (unsigned short*)ws; ws += 524288;
  unsigned short* Wsr_b   = (unsigned short*)ws; ws += 131072;
  unsigned short* regA    = (unsigned short*)ws; ws += 12845056; // pooled bf16
  unsigned short* q_win   = (unsigned short*)ws; ws += 25690112; // q windows
  unsigned short* regC    = (unsigned short*)ws; ws += 12845056; // y2 bf16

  // pool y -> regA | weight converts
  cvt_pool<<<7104, 256, 0, stream>>>(y, regA, Wq, Wkv, Wproj, Wsr,
                                     Wq_b, Wkv_b, Wproj_b, Wsr_b);

  // co-dispatched: q-proj GEMM (196 blocks) + sr conv+LN+GELU (196 blocks)
  qsr_gemm<<<392, 512, 0, stream>>>(x, Wq_b, q_win,
                                    regA, Wsr_b, bsr, gn, bn, regC);

  // mega-fused kv-proj + attention + out-proj (T5 setprio) -> f32 d_out
  kvattn<<<512, 1024, 0, stream>>>(regC, Wkv_b, q_win, Wproj_b, bproj, out);
}